// Round 3
// baseline (12222.550 us; speedup 1.0000x reference)
//
#include <hip/hip_runtime.h>
#include <stdint.h>
#include <stddef.h>

// RNNPredictorBurnin — correctness-first fp32 baseline.
// Mirrors the reference dataflow exactly:
//   for t in 0..63:
//     x   = [e | a_t]                  (e = enc for t=0, else out_{t-1})
//     gi  = x @ W_ih.T + b_ih          (K=1024 part via GEMM, action cols in epilogue)
//     gh  = h @ W_hh.T + b_hh
//     r,z = sigmoid(gi_r+gh_r), sigmoid(gi_z+gh_z)
//     n   = tanh(gi_n + r*gh_n)
//     h   = (1-z)*n + z*h
//     out_t = h @ W_out.T + b_out      (written to d_out; doubles as e_{t+1})
// No bf16, no MFMA, no folding, no swizzle: pure diagnostic bisect.

typedef float f32x4v __attribute__((ext_vector_type(4)));

__global__ __launch_bounds__(256) void init_h(const float* __restrict__ h0,
                                              float* __restrict__ h32) {
    const int idx = blockIdx.x * 256 + threadIdx.x;   // 512*1024 total
    h32[idx] = h0[idx];
}

// C[row0+r][coloff+col0+c] = sum_{k<1024} A[row][k]*Bm[col][k] + bias[col]
//                            (+ act[row][0]*Bm[col][1024] + act[row][1]*Bm[col][1025])
// A: [512][1024] f32. Bm: [N][ldb] f32 row-major. 64x64 tile, 256 thr, 4x4/thr, BK=16.
__global__ __launch_bounds__(256) void gemm_f32(
    const float* __restrict__ A,
    const float* __restrict__ Bm, int ldb,
    const float* __restrict__ bias,
    const float* __restrict__ act,              // [512][2] or nullptr
    float* __restrict__ dst, int dst_stride, int dst_coloff)
{
    __shared__ float As[16][64];
    __shared__ float Bs[16][64];
    const int t  = threadIdx.x;
    const int tx = t & 15, ty = t >> 4;
    const int row0 = blockIdx.y * 64, col0 = blockIdx.x * 64;
    const int lm = t >> 2;              // 0..63 : tile row being staged
    const int lk = (t & 3) * 4;         // 0,4,8,12 : k sub-offset

    float acc[4][4] = {};

    for (int kt = 0; kt < 64; ++kt) {
        const int kbase = kt * 16 + lk;
        // A rows are 4 KB apart (1024 f32) -> 16B-aligned float4 ok
        const f32x4v av = *(const f32x4v*)(A + (size_t)(row0 + lm) * 1024 + kbase);
        // B rows may have ldb=1026 (odd alignment) -> scalar loads
        const float* bp = Bm + (size_t)(col0 + lm) * ldb + kbase;
        const float b0 = bp[0], b1 = bp[1], b2 = bp[2], b3 = bp[3];

        __syncthreads();   // previous iteration's reads complete before overwrite
        As[lk + 0][lm] = av.x; As[lk + 1][lm] = av.y;
        As[lk + 2][lm] = av.z; As[lk + 3][lm] = av.w;
        Bs[lk + 0][lm] = b0;   Bs[lk + 1][lm] = b1;
        Bs[lk + 2][lm] = b2;   Bs[lk + 3][lm] = b3;
        __syncthreads();

#pragma unroll
        for (int kk = 0; kk < 16; ++kk) {
            const f32x4v a4 = *(const f32x4v*)&As[kk][ty * 4];
            const f32x4v b4 = *(const f32x4v*)&Bs[kk][tx * 4];
#pragma unroll
            for (int i = 0; i < 4; ++i)
#pragma unroll
                for (int j = 0; j < 4; ++j)
                    acc[i][j] += a4[i] * b4[j];
        }
    }

#pragma unroll
    for (int i = 0; i < 4; ++i) {
        const int row = row0 + ty * 4 + i;
        float a0 = 0.f, a1 = 0.f;
        if (act) { a0 = act[row * 2]; a1 = act[row * 2 + 1]; }
#pragma unroll
        for (int j = 0; j < 4; ++j) {
            const int col = col0 + tx * 4 + j;
            float v = acc[i][j] + bias[col];
            if (act) v += a0 * Bm[(size_t)col * ldb + 1024]
                        + a1 * Bm[(size_t)col * ldb + 1025];
            dst[(size_t)row * dst_stride + dst_coloff + col] = v;
        }
    }
}

// GRU gate update. gbuf rows [512][6144] = [gi 3072 | gh 3072].
__global__ __launch_bounds__(256) void ew_gru(
    const float* __restrict__ gbuf, float* __restrict__ h32)
{
    const int idx = blockIdx.x * 256 + threadIdx.x;   // 0..524287
    const int b = idx >> 10, j = idx & 1023;
    const float* g = gbuf + (size_t)b * 6144;
    const float pr  = g[j]        + g[3072 + j];
    const float pz  = g[1024 + j] + g[4096 + j];
    const float pni = g[2048 + j];
    const float pnh = g[5120 + j];
    const float r = 1.f / (1.f + expf(-pr));
    const float z = 1.f / (1.f + expf(-pz));
    const float n = tanhf(pni + r * pnh);
    h32[idx] = (1.f - z) * n + z * h32[idx];
}

extern "C" void kernel_launch(void* const* d_in, const int* in_sizes, int n_in,
                              void* d_out, int out_size, void* d_ws, size_t ws_size,
                              hipStream_t stream) {
    const float* enc     = (const float*)d_in[0];
    const float* actions = (const float*)d_in[1];   // [64][512][2]
    const float* h0      = (const float*)d_in[2];   // [1][512][1024]
    const float* W_ih    = (const float*)d_in[3];   // [3072][1026]
    const float* W_hh    = (const float*)d_in[4];   // [3072][1024]
    const float* b_ih    = (const float*)d_in[5];
    const float* b_hh    = (const float*)d_in[6];
    const float* W_out   = (const float*)d_in[7];   // [1024][1024]
    const float* b_out   = (const float*)d_in[8];
    float* out = (float*)d_out;                     // [64][512][1024]
    char* ws = (char*)d_ws;

    float* h32  = (float*)ws;                       // 512*1024 f32   (2 MB)
    float* gbuf = (float*)(ws + 2097152);           // 512*6144 f32   (12.6 MB)

    init_h<<<2048, 256, 0, stream>>>(h0, h32);

    const float* e = enc;
    for (int t = 0; t < 64; ++t) {
        // gi = [e|a_t] @ W_ih.T + b_ih   -> gbuf cols [0,3072)
        gemm_f32<<<dim3(48, 8), 256, 0, stream>>>(
            e, W_ih, 1026, b_ih, actions + (size_t)t * 1024, gbuf, 6144, 0);
        // gh = h @ W_hh.T + b_hh         -> gbuf cols [3072,6144)
        gemm_f32<<<dim3(48, 8), 256, 0, stream>>>(
            h32, W_hh, 1024, b_hh, nullptr, gbuf, 6144, 3072);
        // h = GRU(gi, gh, h)
        ew_gru<<<2048, 256, 0, stream>>>(gbuf, h32);
        // out_t = h @ W_out.T + b_out    -> d_out slice (also e_{t+1})
        float* ot = out + (size_t)t * 524288;
        gemm_f32<<<dim3(16, 8), 256, 0, stream>>>(
            h32, W_out, 1024, b_out, nullptr, ot, 1024, 0);
        e = ot;
    }
}

// Round 6
// 8325.846 us; speedup vs baseline: 1.4680x; 1.4680x over previous
//
#include <hip/hip_runtime.h>
#include <stdint.h>
#include <stddef.h>

// RNNPredictorBurnin — round 6: round-5 kernel with the K-loop bug fixed.
// BUG WAS: gemm_core3 looped (kt&7)*128 bytes -> only k=0..511 of K=1024
// contracted (half of every dot product missing). Fix: 16 k-tiles/third.

typedef __bf16 bf16x8 __attribute__((ext_vector_type(8)));
typedef float f32x4  __attribute__((ext_vector_type(4)));
typedef float f32x4v __attribute__((ext_vector_type(4)));

#define LDS_STRIDE 144          // 128B row + 16B pad (breaks bank conflicts)
#define LDS_TILE   (128 * LDS_STRIDE)   // 18432 B per tile

__device__ __forceinline__ unsigned short f32_bf16(float f) {
    union { float f; unsigned int u; } v; v.f = f;
    unsigned int u = v.u;
    unsigned int r = (u + 0x7fffu + ((u >> 16) & 1u)) >> 16;  // RNE
    return (unsigned short)r;
}
__device__ __forceinline__ float bf16_f32(unsigned short h) {
    union { unsigned int u; float f; } v; v.u = ((unsigned int)h) << 16;
    return v.f;
}
__device__ __forceinline__ void split_bf(float v, unsigned short& hi, unsigned short& lo) {
    hi = f32_bf16(v);
    lo = f32_bf16(v - bf16_f32(hi));
}

// ---------------------------------------------------------------------------
// Split-bf16 3-term GEMM core, 128x128 tile, K=1024 @ ~fp32 accuracy:
// C[m][n] = sum_k (Ahi+Alo)[m][k]*(Bhi+Blo)[n][k] minus lo*lo.
// Thirds {Ahi*Bhi, Ahi*Blo, Alo*Bhi}; 16 k-tiles of 64 bf16 per third (FULL K).
// Staging: each thread loads 64B (4x bf16x8) from global, ds_writes to
// padded LDS. 4 waves 2x2 of 64x64; 16x16x32 bf16 MFMA; acc[4][4] f32x4.
// ---------------------------------------------------------------------------
__device__ __forceinline__ void gemm_core3(
    const unsigned short* __restrict__ Ahi, const unsigned short* __restrict__ Alo,
    const unsigned short* __restrict__ Bhi, const unsigned short* __restrict__ Blo,
    int mrow0, int nrow0,
    char* ldsA, char* ldsB,
    f32x4 (&acc)[4][4])
{
    const int tid  = threadIdx.x;
    const int wid  = tid >> 6;
    const int lane = tid & 63;
    const int wr = wid >> 1, wc = wid & 1;
    const int l16 = lane & 15, lq = lane >> 4;
    const int srow = tid >> 1;          // 0..127 : tile row this thread stages
    const int scol = (tid & 1) * 64;    // byte offset within the 128B row-chunk

    for (int kt = 0; kt < 48; ++kt) {   // 3 thirds x 16 k-tiles of 64 bf16
        const int third = kt >> 4;
        const unsigned short* Ab = (third == 2) ? Alo : Ahi;
        const unsigned short* Bb = (third == 1) ? Blo : Bhi;
        const char* Asrc = (const char*)Ab + (size_t)(mrow0 + srow) * 2048
                         + (kt & 15) * 128 + scol;
        const char* Bsrc = (const char*)Bb + (size_t)(nrow0 + srow) * 2048
                         + (kt & 15) * 128 + scol;
        const bf16x8 a0 = *(const bf16x8*)(Asrc);
        const bf16x8 a1 = *(const bf16x8*)(Asrc + 16);
        const bf16x8 a2 = *(const bf16x8*)(Asrc + 32);
        const bf16x8 a3 = *(const bf16x8*)(Asrc + 48);
        const bf16x8 b0 = *(const bf16x8*)(Bsrc);
        const bf16x8 b1 = *(const bf16x8*)(Bsrc + 16);
        const bf16x8 b2 = *(const bf16x8*)(Bsrc + 32);
        const bf16x8 b3 = *(const bf16x8*)(Bsrc + 48);

        __syncthreads();   // previous iteration's LDS reads complete
        char* da = ldsA + srow * LDS_STRIDE + scol;
        *(bf16x8*)(da)      = a0; *(bf16x8*)(da + 16) = a1;
        *(bf16x8*)(da + 32) = a2; *(bf16x8*)(da + 48) = a3;
        char* db = ldsB + srow * LDS_STRIDE + scol;
        *(bf16x8*)(db)      = b0; *(bf16x8*)(db + 16) = b1;
        *(bf16x8*)(db + 32) = b2; *(bf16x8*)(db + 48) = b3;
        __syncthreads();

#pragma unroll
        for (int kk = 0; kk < 2; ++kk) {
            bf16x8 af[4], bfv[4];
            const int cbr = kk * 64 + lq * 16;
#pragma unroll
            for (int mi = 0; mi < 4; ++mi)
                af[mi] = *(const bf16x8*)(ldsA + (wr * 64 + mi * 16 + l16) * LDS_STRIDE + cbr);
#pragma unroll
            for (int ni = 0; ni < 4; ++ni)
                bfv[ni] = *(const bf16x8*)(ldsB + (wc * 64 + ni * 16 + l16) * LDS_STRIDE + cbr);
#pragma unroll
            for (int mi = 0; mi < 4; ++mi)
#pragma unroll
                for (int ni = 0; ni < 4; ++ni)
                    acc[mi][ni] = __builtin_amdgcn_mfma_f32_16x16x32_bf16(
                        af[mi], bfv[ni], acc[mi][ni], 0, 0, 0);
        }
    }
}

// ---------------------------------------------------------------------------
// Combined gates GEMM: 192 blocks (4 mtiles x 48 ntiles).
// nt<24: gi = e @ W_ih[:, :1024].T + b_ih + a_t @ W_ih[:, 1024:].T
// nt>=24: gh = h @ W_hh.T + b_hh       -> gbuf [512][6144] = [gi | gh]
// ---------------------------------------------------------------------------
__global__ __launch_bounds__(256) void gemm_gates(
    const unsigned short* __restrict__ eh, const unsigned short* __restrict__ el,
    const unsigned short* __restrict__ hh, const unsigned short* __restrict__ hl,
    const unsigned short* __restrict__ Wih_hi, const unsigned short* __restrict__ Wih_lo,
    const unsigned short* __restrict__ Whh_hi, const unsigned short* __restrict__ Whh_lo,
    const float* __restrict__ W_ih,      // fp32 [3072][1026] for action cols
    const float* __restrict__ b_ih, const float* __restrict__ b_hh,
    const float* __restrict__ act,       // actions + t*1024
    float* __restrict__ gbuf)
{
    __shared__ alignas(16) char lds[2 * LDS_TILE];
    const int bid = blockIdx.x;
    const int mt = bid & 3, nt = bid >> 2;      // nt 0..47
    const unsigned short *Ah, *Al, *Bh, *Bl; int nr0;
    if (nt < 24) { Ah = eh; Al = el; Bh = Wih_hi; Bl = Wih_lo; nr0 = nt * 128; }
    else         { Ah = hh; Al = hl; Bh = Whh_hi; Bl = Whh_lo; nr0 = (nt - 24) * 128; }
    f32x4 acc[4][4] = {};
    gemm_core3(Ah, Al, Bh, Bl, mt * 128, nr0, lds, lds + LDS_TILE, acc);

    const int lane = threadIdx.x & 63, wid = threadIdx.x >> 6;
    const int wr = wid >> 1, wc = wid & 1, l16 = lane & 15, lq = lane >> 4;
#pragma unroll
    for (int ni = 0; ni < 4; ++ni) {
        const int ncol = nt * 128 + wc * 64 + ni * 16 + l16;   // 0..6143
        float bias, w0 = 0.f, w1 = 0.f;
        if (ncol < 3072) {
            bias = b_ih[ncol];
            w0 = W_ih[(size_t)ncol * 1026 + 1024];
            w1 = W_ih[(size_t)ncol * 1026 + 1025];
        } else bias = b_hh[ncol - 3072];
#pragma unroll
        for (int mi = 0; mi < 4; ++mi) {
#pragma unroll
            for (int r = 0; r < 4; ++r) {
                const int brow = mt * 128 + wr * 64 + mi * 16 + lq * 4 + r;
                const float v = acc[mi][ni][r] + bias
                              + act[brow * 2] * w0 + act[brow * 2 + 1] * w1;
                gbuf[(size_t)brow * 6144 + ncol] = v;
            }
        }
    }
}

// ---------------------------------------------------------------------------
// Output GEMM: 32 blocks (4 mtiles x 8 ntiles). out_t = h @ W_out.T + b_out.
// Writes fp32 d_out slice AND the split e for the next step's gi.
// ---------------------------------------------------------------------------
__global__ __launch_bounds__(256) void gemm_out(
    const unsigned short* __restrict__ hh, const unsigned short* __restrict__ hl,
    const unsigned short* __restrict__ Wout_hi, const unsigned short* __restrict__ Wout_lo,
    const float* __restrict__ b_out,
    float* __restrict__ outp,
    unsigned short* __restrict__ eh, unsigned short* __restrict__ el)
{
    __shared__ alignas(16) char lds[2 * LDS_TILE];
    const int bid = blockIdx.x;
    const int mt = bid & 3, nt = bid >> 2;      // nt 0..7
    f32x4 acc[4][4] = {};
    gemm_core3(hh, hl, Wout_hi, Wout_lo, mt * 128, nt * 128, lds, lds + LDS_TILE, acc);

    const int lane = threadIdx.x & 63, wid = threadIdx.x >> 6;
    const int wr = wid >> 1, wc = wid & 1, l16 = lane & 15, lq = lane >> 4;
#pragma unroll
    for (int ni = 0; ni < 4; ++ni) {
        const int col = nt * 128 + wc * 64 + ni * 16 + l16;
        const float bias = b_out[col];
#pragma unroll
        for (int mi = 0; mi < 4; ++mi) {
#pragma unroll
            for (int r = 0; r < 4; ++r) {
                const int brow = mt * 128 + wr * 64 + mi * 16 + lq * 4 + r;
                const float v = acc[mi][ni][r] + bias;
                const size_t o = (size_t)brow * 1024 + col;
                outp[o] = v;
                unsigned short hi, lo; split_bf(v, hi, lo);
                eh[o] = hi; el[o] = lo;
            }
        }
    }
}

// ---------------------------------------------------------------------------
// GRU gate update; writes fp32 master h and its bf16 split.
// ---------------------------------------------------------------------------
__global__ __launch_bounds__(256) void ew_gru_split(
    const float* __restrict__ gbuf, float* __restrict__ h32,
    unsigned short* __restrict__ hh, unsigned short* __restrict__ hl)
{
    const int idx = blockIdx.x * 256 + threadIdx.x;   // 0..524287
    const int b = idx >> 10, j = idx & 1023;
    const float* g = gbuf + (size_t)b * 6144;
    const float pr  = g[j]        + g[3072 + j];
    const float pz  = g[1024 + j] + g[4096 + j];
    const float pni = g[2048 + j];
    const float pnh = g[5120 + j];
    const float r = 1.f / (1.f + expf(-pr));
    const float z = 1.f / (1.f + expf(-pz));
    const float n = tanhf(pni + r * pnh);
    const float h = (1.f - z) * n + z * h32[idx];
    h32[idx] = h;
    unsigned short hi, lo; split_bf(h, hi, lo);
    hh[idx] = hi; hl[idx] = lo;
}

// ---------------------------------------------------------------------------
// Prep: weight splits and activation splits.
// ---------------------------------------------------------------------------
__global__ __launch_bounds__(256) void prep_w(
    const float* __restrict__ W_ih, const float* __restrict__ W_hh,
    const float* __restrict__ W_out,
    unsigned short* __restrict__ Wih_hi, unsigned short* __restrict__ Wih_lo,
    unsigned short* __restrict__ Whh_hi, unsigned short* __restrict__ Whh_lo,
    unsigned short* __restrict__ Wout_hi, unsigned short* __restrict__ Wout_lo)
{
    const int idx = blockIdx.x * 256 + threadIdx.x;   // < 3072*1024
    const int n = idx >> 10, k = idx & 1023;
    unsigned short hi, lo;
    split_bf(W_ih[(size_t)n * 1026 + k], hi, lo);
    Wih_hi[idx] = hi; Wih_lo[idx] = lo;
    split_bf(W_hh[idx], hi, lo);
    Whh_hi[idx] = hi; Whh_lo[idx] = lo;
    if (n < 1024) {
        split_bf(W_out[idx], hi, lo);
        Wout_hi[idx] = hi; Wout_lo[idx] = lo;
    }
}

__global__ __launch_bounds__(256) void prep_m(
    const float* __restrict__ enc, const float* __restrict__ h0,
    unsigned short* __restrict__ eh, unsigned short* __restrict__ el,
    unsigned short* __restrict__ hh, unsigned short* __restrict__ hl,
    float* __restrict__ h32)
{
    const int idx = blockIdx.x * 256 + threadIdx.x;   // < 524288
    unsigned short hi, lo;
    split_bf(enc[idx], hi, lo);
    eh[idx] = hi; el[idx] = lo;
    const float hv = h0[idx];
    split_bf(hv, hi, lo);
    hh[idx] = hi; hl[idx] = lo;
    h32[idx] = hv;
}

// ===========================================================================
// fp32 fallback path (round-3 verified), used if ws_size is too small.
// ===========================================================================
__global__ __launch_bounds__(256) void init_h(const float* __restrict__ h0,
                                              float* __restrict__ h32) {
    const int idx = blockIdx.x * 256 + threadIdx.x;
    h32[idx] = h0[idx];
}

__global__ __launch_bounds__(256) void gemm_f32(
    const float* __restrict__ A,
    const float* __restrict__ Bm, int ldb,
    const float* __restrict__ bias,
    const float* __restrict__ act,
    float* __restrict__ dst, int dst_stride, int dst_coloff)
{
    __shared__ float As[16][64];
    __shared__ float Bs[16][64];
    const int t  = threadIdx.x;
    const int tx = t & 15, ty = t >> 4;
    const int row0 = blockIdx.y * 64, col0 = blockIdx.x * 64;
    const int lm = t >> 2;
    const int lk = (t & 3) * 4;
    float acc[4][4] = {};
    for (int kt = 0; kt < 64; ++kt) {
        const int kbase = kt * 16 + lk;
        const f32x4v av = *(const f32x4v*)(A + (size_t)(row0 + lm) * 1024 + kbase);
        const float* bp = Bm + (size_t)(col0 + lm) * ldb + kbase;
        const float b0 = bp[0], b1 = bp[1], b2 = bp[2], b3 = bp[3];
        __syncthreads();
        As[lk + 0][lm] = av.x; As[lk + 1][lm] = av.y;
        As[lk + 2][lm] = av.z; As[lk + 3][lm] = av.w;
        Bs[lk + 0][lm] = b0;   Bs[lk + 1][lm] = b1;
        Bs[lk + 2][lm] = b2;   Bs[lk + 3][lm] = b3;
        __syncthreads();
#pragma unroll
        for (int kk = 0; kk < 16; ++kk) {
            const f32x4v a4 = *(const f32x4v*)&As[kk][ty * 4];
            const f32x4v b4 = *(const f32x4v*)&Bs[kk][tx * 4];
#pragma unroll
            for (int i = 0; i < 4; ++i)
#pragma unroll
                for (int j = 0; j < 4; ++j)
                    acc[i][j] += a4[i] * b4[j];
        }
    }
#pragma unroll
    for (int i = 0; i < 4; ++i) {
        const int row = row0 + ty * 4 + i;
        float a0 = 0.f, a1 = 0.f;
        if (act) { a0 = act[row * 2]; a1 = act[row * 2 + 1]; }
#pragma unroll
        for (int j = 0; j < 4; ++j) {
            const int col = col0 + tx * 4 + j;
            float v = acc[i][j] + bias[col];
            if (act) v += a0 * Bm[(size_t)col * ldb + 1024]
                        + a1 * Bm[(size_t)col * ldb + 1025];
            dst[(size_t)row * dst_stride + dst_coloff + col] = v;
        }
    }
}

__global__ __launch_bounds__(256) void ew_gru32(
    const float* __restrict__ gbuf, float* __restrict__ h32)
{
    const int idx = blockIdx.x * 256 + threadIdx.x;
    const int b = idx >> 10, j = idx & 1023;
    const float* g = gbuf + (size_t)b * 6144;
    const float pr  = g[j]        + g[3072 + j];
    const float pz  = g[1024 + j] + g[4096 + j];
    const float pni = g[2048 + j];
    const float pnh = g[5120 + j];
    const float r = 1.f / (1.f + expf(-pr));
    const float z = 1.f / (1.f + expf(-pz));
    const float n = tanhf(pni + r * pnh);
    h32[idx] = (1.f - z) * n + z * h32[idx];
}

// ---------------------------------------------------------------------------
extern "C" void kernel_launch(void* const* d_in, const int* in_sizes, int n_in,
                              void* d_out, int out_size, void* d_ws, size_t ws_size,
                              hipStream_t stream) {
    const float* enc     = (const float*)d_in[0];
    const float* actions = (const float*)d_in[1];   // [64][512][2]
    const float* h0      = (const float*)d_in[2];
    const float* W_ih    = (const float*)d_in[3];   // [3072][1026]
    const float* W_hh    = (const float*)d_in[4];   // [3072][1024]
    const float* b_ih    = (const float*)d_in[5];
    const float* b_hh    = (const float*)d_in[6];
    const float* W_out   = (const float*)d_in[7];   // [1024][1024]
    const float* b_out   = (const float*)d_in[8];
    float* out = (float*)d_out;                     // [64][512][1024]
    char* ws = (char*)d_ws;

    float* h32  = (float*)ws;                       // 2,097,152 B
    float* gbuf = (float*)(ws + 2097152);           // 12,582,912 B -> 14,680,064

    const size_t NEED = 48234496;
    if (ws_size < NEED) {
        // ---------------- fp32 fallback (round-3 verified) ----------------
        init_h<<<2048, 256, 0, stream>>>(h0, h32);
        const float* e = enc;
        for (int t = 0; t < 64; ++t) {
            gemm_f32<<<dim3(48, 8), 256, 0, stream>>>(
                e, W_ih, 1026, b_ih, actions + (size_t)t * 1024, gbuf, 6144, 0);
            gemm_f32<<<dim3(48, 8), 256, 0, stream>>>(
                h32, W_hh, 1024, b_hh, nullptr, gbuf, 6144, 3072);
            ew_gru32<<<2048, 256, 0, stream>>>(gbuf, h32);
            float* ot = out + (size_t)t * 524288;
            gemm_f32<<<dim3(16, 8), 256, 0, stream>>>(
                h32, W_out, 1024, b_out, nullptr, ot, 1024, 0);
            e = ot;
        }
        return;
    }

    // ---------------- split-bf16 MFMA path ----------------
    size_t off = 14680064;
    auto take = [&](size_t bytes) { char* p = ws + off; off += bytes; return p; };
    unsigned short* Wih_hi  = (unsigned short*)take(6291456);
    unsigned short* Wih_lo  = (unsigned short*)take(6291456);
    unsigned short* Whh_hi  = (unsigned short*)take(6291456);
    unsigned short* Whh_lo  = (unsigned short*)take(6291456);
    unsigned short* Wout_hi = (unsigned short*)take(2097152);
    unsigned short* Wout_lo = (unsigned short*)take(2097152);
    unsigned short* eh      = (unsigned short*)take(1048576);
    unsigned short* el      = (unsigned short*)take(1048576);
    unsigned short* hh      = (unsigned short*)take(1048576);
    unsigned short* hl      = (unsigned short*)take(1048576);
    // off == 48,234,496

    prep_w<<<12288, 256, 0, stream>>>(W_ih, W_hh, W_out,
        Wih_hi, Wih_lo, Whh_hi, Whh_lo, Wout_hi, Wout_lo);
    prep_m<<<2048, 256, 0, stream>>>(enc, h0, eh, el, hh, hl, h32);

    for (int t = 0; t < 64; ++t) {
        gemm_gates<<<192, 256, 0, stream>>>(eh, el, hh, hl,
            Wih_hi, Wih_lo, Whh_hi, Whh_lo,
            W_ih, b_ih, b_hh, actions + (size_t)t * 1024, gbuf);
        ew_gru_split<<<2048, 256, 0, stream>>>(gbuf, h32, hh, hl);
        gemm_out<<<32, 256, 0, stream>>>(hh, hl, Wout_hi, Wout_lo, b_out,
            out + (size_t)t * 524288, eh, el);
    }
}

// Round 8
// 6911.282 us; speedup vs baseline: 1.7685x; 1.2047x over previous
//
#include <hip/hip_runtime.h>
#include <stdint.h>
#include <stddef.h>

// RNNPredictorBurnin — round 8: folded step + 3-way bf16 splits (6-term GEMM,
// residual 2^-27 ~ fp32-grade) + fp32 W_comb (VALU, one-time) + fp32 t=0.
// Per step t>=1: ONE 160-block MFMA GEMM [rz | gi_n | gh_n | out_{t-1}] + ew.

typedef __bf16 bf16x8 __attribute__((ext_vector_type(8)));
typedef float f32x4  __attribute__((ext_vector_type(4)));

#define LDS_STRIDE 144                  // 128B row + 16B pad
#define LDS_TILE   (128 * LDS_STRIDE)   // 18432 B

__device__ __forceinline__ unsigned short f32_bf16(float f) {
    union { float f; unsigned int u; } v; v.f = f;
    unsigned int u = v.u;
    unsigned int r = (u + 0x7fffu + ((u >> 16) & 1u)) >> 16;  // RNE
    return (unsigned short)r;
}
__device__ __forceinline__ float bf16_f32(unsigned short h) {
    union { unsigned int u; float f; } v; v.u = ((unsigned int)h) << 16;
    return v.f;
}
__device__ __forceinline__ void split3(float v, unsigned short& a,
                                       unsigned short& b, unsigned short& c) {
    a = f32_bf16(v);
    const float r1 = v - bf16_f32(a);
    b = f32_bf16(r1);
    const float r2 = r1 - bf16_f32(b);
    c = f32_bf16(r2);
}

// ---------------------------------------------------------------------------
// 6-term 3-plane split GEMM core, 128x128 tile, K=1024, residual ~2^-27:
// C = sum over (a,b) in {(0,0),(0,1),(1,0),(1,1),(0,2),(2,0)} of Aa*Bb.
// 96 k-iterations (6 segs x 16 k-tiles of 64 bf16). Register prefetch of
// chunk kt+1 before consuming chunk kt hides global latency.
// ---------------------------------------------------------------------------
__device__ __forceinline__ void load_chunk6(
    const unsigned short* __restrict__ A0, const unsigned short* __restrict__ A1,
    const unsigned short* __restrict__ A2,
    const unsigned short* __restrict__ B0, const unsigned short* __restrict__ B1,
    const unsigned short* __restrict__ B2,
    int mrow0, int nrow0, int srow, int scol, int kt,
    bf16x8 (&ra)[4], bf16x8 (&rb)[4])
{
    const int seg = kt >> 4;   // 0:(0,0) 1:(0,1) 2:(1,0) 3:(1,1) 4:(0,2) 5:(2,0)
    const unsigned short* Ab = (seg == 5) ? A2 : ((seg == 2 || seg == 3) ? A1 : A0);
    const unsigned short* Bb = (seg == 4) ? B2 : ((seg == 1 || seg == 3) ? B1 : B0);
    const char* Asrc = (const char*)Ab + (size_t)(mrow0 + srow) * 2048
                     + (kt & 15) * 128 + scol;
    const char* Bsrc = (const char*)Bb + (size_t)(nrow0 + srow) * 2048
                     + (kt & 15) * 128 + scol;
    ra[0] = *(const bf16x8*)(Asrc);      ra[1] = *(const bf16x8*)(Asrc + 16);
    ra[2] = *(const bf16x8*)(Asrc + 32); ra[3] = *(const bf16x8*)(Asrc + 48);
    rb[0] = *(const bf16x8*)(Bsrc);      rb[1] = *(const bf16x8*)(Bsrc + 16);
    rb[2] = *(const bf16x8*)(Bsrc + 32); rb[3] = *(const bf16x8*)(Bsrc + 48);
}

__device__ __forceinline__ void gemm_core6(
    const unsigned short* __restrict__ A0, const unsigned short* __restrict__ A1,
    const unsigned short* __restrict__ A2,
    const unsigned short* __restrict__ B0, const unsigned short* __restrict__ B1,
    const unsigned short* __restrict__ B2,
    int mrow0, int nrow0,
    char* ldsA, char* ldsB,
    f32x4 (&acc)[4][4])
{
    const int tid  = threadIdx.x;
    const int wid  = tid >> 6;
    const int lane = tid & 63;
    const int wr = wid >> 1, wc = wid & 1;
    const int l16 = lane & 15, lq = lane >> 4;
    const int srow = tid >> 1;
    const int scol = (tid & 1) * 64;

    bf16x8 pa[4], pb[4], na[4], nb[4];
    load_chunk6(A0, A1, A2, B0, B1, B2, mrow0, nrow0, srow, scol, 0, pa, pb);

    for (int kt = 0; kt < 96; ++kt) {
        if (kt < 95)
            load_chunk6(A0, A1, A2, B0, B1, B2, mrow0, nrow0, srow, scol, kt + 1, na, nb);
        __syncthreads();                 // prev iteration's LDS reads complete
        char* da = ldsA + srow * LDS_STRIDE + scol;
        *(bf16x8*)(da)      = pa[0]; *(bf16x8*)(da + 16) = pa[1];
        *(bf16x8*)(da + 32) = pa[2]; *(bf16x8*)(da + 48) = pa[3];
        char* db = ldsB + srow * LDS_STRIDE + scol;
        *(bf16x8*)(db)      = pb[0]; *(bf16x8*)(db + 16) = pb[1];
        *(bf16x8*)(db + 32) = pb[2]; *(bf16x8*)(db + 48) = pb[3];
        __syncthreads();

#pragma unroll
        for (int kk = 0; kk < 2; ++kk) {
            bf16x8 af[4], bfv[4];
            const int cbr = kk * 64 + lq * 16;
#pragma unroll
            for (int mi = 0; mi < 4; ++mi)
                af[mi] = *(const bf16x8*)(ldsA + (wr * 64 + mi * 16 + l16) * LDS_STRIDE + cbr);
#pragma unroll
            for (int ni = 0; ni < 4; ++ni)
                bfv[ni] = *(const bf16x8*)(ldsB + (wc * 64 + ni * 16 + l16) * LDS_STRIDE + cbr);
#pragma unroll
            for (int mi = 0; mi < 4; ++mi)
#pragma unroll
                for (int ni = 0; ni < 4; ++ni)
                    acc[mi][ni] = __builtin_amdgcn_mfma_f32_16x16x32_bf16(
                        af[mi], bfv[ni], acc[mi][ni], 0, 0, 0);
        }
        if (kt < 95) {
#pragma unroll
            for (int j = 0; j < 4; ++j) { pa[j] = na[j]; pb[j] = nb[j]; }
        }
    }
}

// ---------------------------------------------------------------------------
// Folded step GEMM. A = h_t (3 planes). B = Wbig (3 planes) rows:
// [0,2048) rz = W_comb+W_hh ; [2048,3072) gi_n = W_comb ;
// [3072,4096) gh_n = W_hh[2048:3072] ; [4096,5120) W_out.
// n<4096 -> gbuf (stride 4096) ; n>=4096 -> outp (= out_{t-1}).
// ---------------------------------------------------------------------------
__global__ __launch_bounds__(256) void gemm_step6(
    const unsigned short* __restrict__ h0p, const unsigned short* __restrict__ h1p,
    const unsigned short* __restrict__ h2p,
    const unsigned short* __restrict__ W0, const unsigned short* __restrict__ W1,
    const unsigned short* __restrict__ W2,
    float* __restrict__ gbuf, float* __restrict__ outp,
    const float* __restrict__ bias_big,
    const float* __restrict__ W_ih,      // fp32 [3072][1026], action cols
    const float* __restrict__ act,       // actions + t*1024
    int col_base)
{
    __shared__ alignas(16) char lds[2 * LDS_TILE];
    const int bid = blockIdx.x;
    int mt, nt;
    if (col_base) { mt = bid & 3; nt = bid >> 2; }            // final: 32 blocks
    else { const int xcd = bid & 7, loc = bid >> 3;           // steps: 160 blocks
           mt = loc & 3; nt = xcd * 5 + (loc >> 2); }
    f32x4 acc[4][4] = {};
    gemm_core6(h0p, h1p, h2p, W0, W1, W2,
               mt * 128, col_base + nt * 128, lds, lds + LDS_TILE, acc);

    const int lane = threadIdx.x & 63, wid = threadIdx.x >> 6;
    const int wr = wid >> 1, wc = wid & 1, l16 = lane & 15, lq = lane >> 4;
#pragma unroll
    for (int ni = 0; ni < 4; ++ni) {
        const int n = col_base + nt * 128 + wc * 64 + ni * 16 + l16;
        const float bias = bias_big[n];
        float w0 = 0.f, w1 = 0.f;
        if (n < 3072) { w0 = W_ih[(size_t)n * 1026 + 1024];
                        w1 = W_ih[(size_t)n * 1026 + 1025]; }
#pragma unroll
        for (int mi = 0; mi < 4; ++mi) {
#pragma unroll
            for (int r = 0; r < 4; ++r) {
                const int brow = mt * 128 + wr * 64 + mi * 16 + lq * 4 + r;
                const float v = acc[mi][ni][r] + bias
                              + act[brow * 2] * w0 + act[brow * 2 + 1] * w1;
                if (n < 4096) gbuf[(size_t)brow * 4096 + n] = v;
                else          outp[(size_t)brow * 1024 + (n - 4096)] = v;
            }
        }
    }
}

// ---------------------------------------------------------------------------
// GRU updates
// ---------------------------------------------------------------------------
__global__ __launch_bounds__(256) void ew_fold6(
    const float* __restrict__ gbuf, float* __restrict__ h32,
    unsigned short* __restrict__ h0p, unsigned short* __restrict__ h1p,
    unsigned short* __restrict__ h2p)
{
    const int idx = blockIdx.x * 256 + threadIdx.x;   // 0..524287
    const int b = idx >> 10, j = idx & 1023;
    const float* g = gbuf + (size_t)b * 4096;
    const float r = 1.f / (1.f + expf(-g[j]));
    const float z = 1.f / (1.f + expf(-g[1024 + j]));
    const float n = tanhf(g[2048 + j] + r * g[3072 + j]);
    const float h = (1.f - z) * n + z * h32[idx];
    h32[idx] = h;
    split3(h, h0p[idx], h1p[idx], h2p[idx]);
}

__global__ __launch_bounds__(256) void ew_t0_32(
    const float* __restrict__ gbuf, float* __restrict__ h32,
    unsigned short* __restrict__ h0p, unsigned short* __restrict__ h1p,
    unsigned short* __restrict__ h2p)
{
    const int idx = blockIdx.x * 256 + threadIdx.x;   // 0..524287
    const int b = idx >> 10, j = idx & 1023;
    const float* g = gbuf + (size_t)b * 6144;
    const float pr  = g[j]        + g[3072 + j];
    const float pz  = g[1024 + j] + g[4096 + j];
    const float r = 1.f / (1.f + expf(-pr));
    const float z = 1.f / (1.f + expf(-pz));
    const float n = tanhf(g[2048 + j] + r * g[5120 + j]);
    const float h = (1.f - z) * n + z * h32[idx];
    h32[idx] = h;
    split3(h, h0p[idx], h1p[idx], h2p[idx]);
}

// ---------------------------------------------------------------------------
// Prep kernels
// ---------------------------------------------------------------------------
__global__ __launch_bounds__(256) void transpose_wout(
    const float* __restrict__ W_out, float* __restrict__ WoutT)
{
    const int idx = blockIdx.x * 256 + threadIdx.x;   // < 1024*1024
    const int o = idx >> 10, c = idx & 1023;
    WoutT[(size_t)c * 1024 + o] = W_out[idx];
}

// Build Wbig (5120x1024) 3-plane split from fp32 sources.
__global__ __launch_bounds__(256) void prep_wbig(
    const float* __restrict__ wcomb,     // [3072][1024] fp32
    const float* __restrict__ W_hh,      // [3072][1024] fp32
    const float* __restrict__ W_out,     // [1024][1024] fp32
    unsigned short* __restrict__ W0, unsigned short* __restrict__ W1,
    unsigned short* __restrict__ W2)
{
    const int idx = blockIdx.x * 256 + threadIdx.x;   // < 5120*1024
    const int row = idx >> 10, col = idx & 1023;
    float v;
    if (row < 2048)      v = wcomb[idx] + W_hh[idx];
    else if (row < 3072) v = wcomb[idx];
    else if (row < 4096) v = W_hh[(size_t)(row - 1024) * 1024 + col];
    else                 v = W_out[(size_t)(row - 4096) * 1024 + col];
    split3(v, W0[idx], W1[idx], W2[idx]);
}

__global__ __launch_bounds__(256) void prep_bias(
    const float* __restrict__ W_ih,
    const float* __restrict__ b_ih, const float* __restrict__ b_hh,
    const float* __restrict__ b_out,
    float* __restrict__ bias_big)
{
    const int n = blockIdx.x * 256 + threadIdx.x;     // < 5120
    if (n >= 5120) return;
    float v;
    if (n < 3072) {
        float d = 0.f;
        for (int o = 0; o < 1024; ++o) d += W_ih[(size_t)n * 1026 + o] * b_out[o];
        v = b_ih[n] + d + (n < 2048 ? b_hh[n] : 0.f);
    } else if (n < 4096) v = b_hh[n - 1024];
    else                 v = b_out[n - 4096];
    bias_big[n] = v;
}

__global__ __launch_bounds__(256) void init_h3(
    const float* __restrict__ h0, float* __restrict__ h32,
    unsigned short* __restrict__ h0p, unsigned short* __restrict__ h1p,
    unsigned short* __restrict__ h2p)
{
    const int idx = blockIdx.x * 256 + threadIdx.x;   // < 524288
    const float hv = h0[idx];
    h32[idx] = hv;
    split3(hv, h0p[idx], h1p[idx], h2p[idx]);
}

// ===========================================================================
// fp32 vector GEMM (round-3 verified, + lda param, scalar A loads).
// Used for t=0, the one-time W_comb, and the full fallback path.
// ===========================================================================
__global__ __launch_bounds__(256) void gemm_f32(
    const float* __restrict__ A, int lda,
    const float* __restrict__ Bm, int ldb,
    const float* __restrict__ bias,
    const float* __restrict__ act,
    float* __restrict__ dst, int dst_stride, int dst_coloff)
{
    __shared__ float As[16][64];
    __shared__ float Bs[16][64];
    const int t  = threadIdx.x;
    const int tx = t & 15, ty = t >> 4;
    const int row0 = blockIdx.y * 64, col0 = blockIdx.x * 64;
    const int lm = t >> 2;
    const int lk = (t & 3) * 4;
    float acc[4][4] = {};
    for (int kt = 0; kt < 64; ++kt) {
        const int kbase = kt * 16 + lk;
        const float* ap = A + (size_t)(row0 + lm) * lda + kbase;
        const float a0 = ap[0], a1 = ap[1], a2 = ap[2], a3 = ap[3];
        const float* bp = Bm + (size_t)(col0 + lm) * ldb + kbase;
        const float b0 = bp[0], b1 = bp[1], b2 = bp[2], b3 = bp[3];
        __syncthreads();
        As[lk + 0][lm] = a0;   As[lk + 1][lm] = a1;
        As[lk + 2][lm] = a2;   As[lk + 3][lm] = a3;
        Bs[lk + 0][lm] = b0;   Bs[lk + 1][lm] = b1;
        Bs[lk + 2][lm] = b2;   Bs[lk + 3][lm] = b3;
        __syncthreads();
#pragma unroll
        for (int kk = 0; kk < 16; ++kk) {
            const f32x4 a4 = *(const f32x4*)&As[kk][ty * 4];
            const f32x4 b4 = *(const f32x4*)&Bs[kk][tx * 4];
#pragma unroll
            for (int i = 0; i < 4; ++i)
#pragma unroll
                for (int j = 0; j < 4; ++j)
                    acc[i][j] += a4[i] * b4[j];
        }
    }
#pragma unroll
    for (int i = 0; i < 4; ++i) {
        const int row = row0 + ty * 4 + i;
        float a0 = 0.f, a1 = 0.f;
        if (act) { a0 = act[row * 2]; a1 = act[row * 2 + 1]; }
#pragma unroll
        for (int j = 0; j < 4; ++j) {
            const int col = col0 + tx * 4 + j;
            float v = acc[i][j] + (bias ? bias[col] : 0.f);
            if (act) v += a0 * Bm[(size_t)col * ldb + 1024]
                        + a1 * Bm[(size_t)col * ldb + 1025];
            dst[(size_t)row * dst_stride + dst_coloff + col] = v;
        }
    }
}

__global__ __launch_bounds__(256) void ew_gru32(
    const float* __restrict__ gbuf, float* __restrict__ h32)
{
    const int idx = blockIdx.x * 256 + threadIdx.x;
    const int b = idx >> 10, j = idx & 1023;
    const float* g = gbuf + (size_t)b * 6144;
    const float pr  = g[j]        + g[3072 + j];
    const float pz  = g[1024 + j] + g[4096 + j];
    const float r = 1.f / (1.f + expf(-pr));
    const float z = 1.f / (1.f + expf(-pz));
    const float n = tanhf(g[2048 + j] + r * g[5120 + j]);
    h32[idx] = (1.f - z) * n + z * h32[idx];
}

__global__ __launch_bounds__(256) void init_h(const float* __restrict__ h0,
                                              float* __restrict__ h32) {
    const int idx = blockIdx.x * 256 + threadIdx.x;
    h32[idx] = h0[idx];
}

// ---------------------------------------------------------------------------
extern "C" void kernel_launch(void* const* d_in, const int* in_sizes, int n_in,
                              void* d_out, int out_size, void* d_ws, size_t ws_size,
                              hipStream_t stream) {
    const float* enc     = (const float*)d_in[0];
    const float* actions = (const float*)d_in[1];   // [64][512][2]
    const float* h0      = (const float*)d_in[2];
    const float* W_ih    = (const float*)d_in[3];   // [3072][1026]
    const float* W_hh    = (const float*)d_in[4];   // [3072][1024]
    const float* b_ih    = (const float*)d_in[5];
    const float* b_hh    = (const float*)d_in[6];
    const float* W_out   = (const float*)d_in[7];   // [1024][1024]
    const float* b_out   = (const float*)d_in[8];
    float* out = (float*)d_out;                     // [64][512][1024]
    char* ws = (char*)d_ws;

    float* h32  = (float*)ws;                       // 2,097,152 B
    float* gbuf = (float*)(ws + 2097152);           // 12,582,912 -> 14,680,064

    const size_t NEED = 66080768;
    if (ws_size < NEED) {
        // ---------------- fp32 fallback (round-3 verified) ----------------
        init_h<<<2048, 256, 0, stream>>>(h0, h32);
        const float* e = enc;
        for (int t = 0; t < 64; ++t) {
            gemm_f32<<<dim3(48, 8), 256, 0, stream>>>(
                e, 1024, W_ih, 1026, b_ih, actions + (size_t)t * 1024, gbuf, 6144, 0);
            gemm_f32<<<dim3(48, 8), 256, 0, stream>>>(
                h32, 1024, W_hh, 1024, b_hh, nullptr, gbuf, 6144, 3072);
            ew_gru32<<<2048, 256, 0, stream>>>(gbuf, h32);
            float* ot = out + (size_t)t * 524288;
            gemm_f32<<<dim3(16, 8), 256, 0, stream>>>(
                h32, 1024, W_out, 1024, b_out, nullptr, ot, 1024, 0);
            e = ot;
        }
        return;
    }

    // ---------------- 3-plane split MFMA path ----------------
    size_t off = 14680064;
    auto take = [&](size_t bytes) { char* p = ws + off; off += bytes; return p; };
    unsigned short* W0   = (unsigned short*)take(10485760);   // 5120x1024
    unsigned short* W1   = (unsigned short*)take(10485760);
    unsigned short* W2   = (unsigned short*)take(10485760);
    unsigned short* h0p  = (unsigned short*)take(1048576);    // 512x1024
    unsigned short* h1p  = (unsigned short*)take(1048576);
    unsigned short* h2p  = (unsigned short*)take(1048576);
    float* WoutT         = (float*)take(4194304);             // 1024x1024 f32
    float* wcomb         = (float*)take(12582912);            // 3072x1024 f32
    float* bias_big      = (float*)take(20480);               // 5120 f32
    // off == 66,080,768

    // One-time prep: W_comb = W_ih[:, :1024] @ W_out (fp32), Wbig planes, bias.
    transpose_wout<<<4096, 256, 0, stream>>>(W_out, WoutT);
    gemm_f32<<<dim3(16, 48), 256, 0, stream>>>(
        W_ih, 1026, WoutT, 1024, nullptr, nullptr, wcomb, 1024, 0);
    prep_wbig<<<20480, 256, 0, stream>>>(wcomb, W_hh, W_out, W0, W1, W2);
    prep_bias<<<20, 256, 0, stream>>>(W_ih, b_ih, b_hh, b_out, bias_big);
    init_h3<<<2048, 256, 0, stream>>>(h0, h32, h0p, h1p, h2p);

    // t = 0 in fp32 (e = enc), then split h_1.
    gemm_f32<<<dim3(48, 8), 256, 0, stream>>>(
        enc, 1024, W_ih, 1026, b_ih, actions, gbuf, 6144, 0);
    gemm_f32<<<dim3(48, 8), 256, 0, stream>>>(
        h32, 1024, W_hh, 1024, b_hh, nullptr, gbuf, 6144, 3072);
    ew_t0_32<<<2048, 256, 0, stream>>>(gbuf, h32, h0p, h1p, h2p);

    // t = 1..63: one folded GEMM (gates_t + out_{t-1}) + ew.
    for (int t = 1; t < 64; ++t) {
        gemm_step6<<<160, 256, 0, stream>>>(h0p, h1p, h2p, W0, W1, W2, gbuf,
                                            out + (size_t)(t - 1) * 524288,
                                            bias_big, W_ih,
                                            actions + (size_t)t * 1024, 0);
        ew_fold6<<<2048, 256, 0, stream>>>(gbuf, h32, h0p, h1p, h2p);
    }
    // out_63 = h_64 @ W_out.T + b_out
    gemm_step6<<<32, 256, 0, stream>>>(h0p, h1p, h2p, W0, W1, W2, gbuf,
                                       out + (size_t)63 * 524288,
                                       bias_big, W_ih, actions, 4096);
}

// Round 9
// 5732.877 us; speedup vs baseline: 2.1320x; 1.2056x over previous
//
#include <hip/hip_runtime.h>
#include <stdint.h>
#include <stddef.h>

// RNNPredictorBurnin — round 9: f16 2-plane scaled split (3 terms, 2^-22),
// XOR-swizzled LDS (kills r8's 8-way pad-conflict), 320-block grid.
// Dataflow identical to r8 (folded W_comb step GEMM + ew), fp32 fallback kept.
//
// Split:  A ~= A0 + A1/2048        (A0=f16(v), A1=f16((v-A0)*2048))
//         16*B ~= B0 + B1/2048     (weights pre-scaled x16 -> f16-normal range)
// Step:   C = (acc0 + accL/2048)/16,  acc0 += A0*B0, accL += A0*B1 + A1*B0

typedef _Float16 f16x8 __attribute__((ext_vector_type(8)));
typedef float f32x4  __attribute__((ext_vector_type(4)));

__device__ __forceinline__ void split2h(float v, _Float16& a, _Float16& b) {
    a = (_Float16)v;
    b = (_Float16)((v - (float)a) * 2048.0f);
}

// ---------------------------------------------------------------------------
// 3-term f16 GEMM core, 128x64 tile, K=1024 (48 k-iters: 16 per segment).
// seg 0: A0*B0 -> acc0 ; seg 1: A0*B1 -> accL ; seg 2: A1*B0 -> accL.
// LDS XOR swizzle: addr = row*128 + (col ^ ((row&7)<<4)), write & read sides.
// Register prefetch of chunk kt+1 before consuming chunk kt.
// ---------------------------------------------------------------------------
__device__ __forceinline__ void load_chunk16(
    const _Float16* __restrict__ A0, const _Float16* __restrict__ A1,
    const _Float16* __restrict__ B0, const _Float16* __restrict__ B1,
    int mrow0, int nrow0, int arow, int acol, int brow, int bcol, int kt,
    f16x8 (&ra)[4], f16x8 (&rb)[2])
{
    const int seg = kt >> 4;                       // 0,1,2
    const _Float16* Ab = (seg == 2) ? A1 : A0;
    const _Float16* Bb = (seg == 1) ? B1 : B0;
    const int koff = (kt & 15) * 128;
    const char* Asrc = (const char*)Ab + (size_t)(mrow0 + arow) * 2048 + koff + acol;
    const char* Bsrc = (const char*)Bb + (size_t)(nrow0 + brow) * 2048 + koff + bcol;
    ra[0] = *(const f16x8*)(Asrc);      ra[1] = *(const f16x8*)(Asrc + 16);
    ra[2] = *(const f16x8*)(Asrc + 32); ra[3] = *(const f16x8*)(Asrc + 48);
    rb[0] = *(const f16x8*)(Bsrc);      rb[1] = *(const f16x8*)(Bsrc + 16);
}

__device__ __forceinline__ int swz(int row, int col) {   // LDS byte address
    return row * 128 + (col ^ ((row & 7) << 4));
}

__device__ __forceinline__ void gemm_core16(
    const _Float16* __restrict__ A0, const _Float16* __restrict__ A1,
    const _Float16* __restrict__ B0, const _Float16* __restrict__ B1,
    int mrow0, int nrow0,
    char* ldsA, char* ldsB,
    f32x4 (&acc0)[4][2], f32x4 (&accL)[4][2])
{
    const int tid  = threadIdx.x;
    const int wid  = tid >> 6;
    const int lane = tid & 63;
    const int wr = wid >> 1, wc = wid & 1;
    const int l16 = lane & 15, lq = lane >> 4;
    const int arow = tid >> 1, acol = (tid & 1) * 64;   // A: 128 rows x 128B
    const int brow = tid >> 2, bcol = (tid & 3) * 32;   // B: 64 rows x 128B

    f16x8 pa[4], pb[2], na[4], nb[2];
    load_chunk16(A0, A1, B0, B1, mrow0, nrow0, arow, acol, brow, bcol, 0, pa, pb);

    for (int kt = 0; kt < 48; ++kt) {
        if (kt < 47)
            load_chunk16(A0, A1, B0, B1, mrow0, nrow0, arow, acol, brow, bcol,
                         kt + 1, na, nb);
        __syncthreads();
#pragma unroll
        for (int i = 0; i < 4; ++i)
            *(f16x8*)(ldsA + swz(arow, acol + i * 16)) = pa[i];
#pragma unroll
        for (int i = 0; i < 2; ++i)
            *(f16x8*)(ldsB + swz(brow, bcol + i * 16)) = pb[i];
        __syncthreads();

        f32x4 (*accp)[2] = (kt < 16) ? acc0 : accL;
#pragma unroll
        for (int kk = 0; kk < 2; ++kk) {
            f16x8 af[4], bf[2];
            const int col = kk * 64 + lq * 16;
#pragma unroll
            for (int mi = 0; mi < 4; ++mi)
                af[mi] = *(const f16x8*)(ldsA + swz(wr * 64 + mi * 16 + l16, col));
#pragma unroll
            for (int ni = 0; ni < 2; ++ni)
                bf[ni] = *(const f16x8*)(ldsB + swz(wc * 32 + ni * 16 + l16, col));
#pragma unroll
            for (int mi = 0; mi < 4; ++mi)
#pragma unroll
                for (int ni = 0; ni < 2; ++ni)
                    accp[mi][ni] = __builtin_amdgcn_mfma_f32_16x16x32_f16(
                        af[mi], bf[ni], accp[mi][ni], 0, 0, 0);
        }
        if (kt < 47) {
#pragma unroll
            for (int j = 0; j < 4; ++j) pa[j] = na[j];
#pragma unroll
            for (int j = 0; j < 2; ++j) pb[j] = nb[j];
        }
    }
}

// ---------------------------------------------------------------------------
// Folded step GEMM. A = h (2 f16 planes). B = Wbig*16 (2 f16 planes) rows:
// [0,2048) rz = W_comb+W_hh ; [2048,3072) gi_n = W_comb ;
// [3072,4096) gh_n = W_hh[2048:3072] ; [4096,5120) W_out.
// Step grid: 320 blocks (4 mt x 80 nt, XCD-contiguous nt). Final: 64 blocks.
// ---------------------------------------------------------------------------
__global__ __launch_bounds__(256) void gemm_step16(
    const _Float16* __restrict__ hA0, const _Float16* __restrict__ hA1,
    const _Float16* __restrict__ W0, const _Float16* __restrict__ W1,
    float* __restrict__ gbuf, float* __restrict__ outp,
    const float* __restrict__ bias_big,
    const float* __restrict__ W_ih,      // fp32 [3072][1026], action cols
    const float* __restrict__ act,       // actions + t*1024
    int col_base)
{
    __shared__ alignas(16) char lds[24576];   // A 16KB + B 8KB
    const int bid = blockIdx.x;
    int mt, nt;
    if (col_base) { mt = bid & 3; nt = bid >> 2; }            // 64 blocks, nt 0..15
    else { const int xcd = bid & 7, loc = bid >> 3;           // 320 blocks
           mt = loc & 3; nt = xcd * 10 + (loc >> 2); }        // nt 0..79
    f32x4 acc0[4][2] = {}, accL[4][2] = {};
    gemm_core16(hA0, hA1, W0, W1, mt * 128, col_base + nt * 64,
                lds, lds + 16384, acc0, accL);

    const int lane = threadIdx.x & 63, wid = threadIdx.x >> 6;
    const int wr = wid >> 1, wc = wid & 1, l16 = lane & 15, lq = lane >> 4;
#pragma unroll
    for (int ni = 0; ni < 2; ++ni) {
        const int n = col_base + nt * 64 + wc * 32 + ni * 16 + l16;
        const float bias = bias_big[n];
        float w0 = 0.f, w1 = 0.f;
        if (n < 3072) { w0 = W_ih[(size_t)n * 1026 + 1024];
                        w1 = W_ih[(size_t)n * 1026 + 1025]; }
#pragma unroll
        for (int mi = 0; mi < 4; ++mi) {
#pragma unroll
            for (int r = 0; r < 4; ++r) {
                const int brow = mt * 128 + wr * 64 + mi * 16 + lq * 4 + r;
                const float dot = (acc0[mi][ni][r] + accL[mi][ni][r] * (1.f/2048.f))
                                  * (1.f/16.f);
                const float v = dot + bias
                              + act[brow * 2] * w0 + act[brow * 2 + 1] * w1;
                if (n < 4096) gbuf[(size_t)brow * 4096 + n] = v;
                else          outp[(size_t)brow * 1024 + (n - 4096)] = v;
            }
        }
    }
}

// ---------------------------------------------------------------------------
// GRU updates (write f16 planes of h)
// ---------------------------------------------------------------------------
__global__ __launch_bounds__(256) void ew_fold16(
    const float* __restrict__ gbuf, float* __restrict__ h32,
    _Float16* __restrict__ hA0, _Float16* __restrict__ hA1)
{
    const int idx = blockIdx.x * 256 + threadIdx.x;   // 0..524287
    const int b = idx >> 10, j = idx & 1023;
    const float* g = gbuf + (size_t)b * 4096;
    const float r = 1.f / (1.f + expf(-g[j]));
    const float z = 1.f / (1.f + expf(-g[1024 + j]));
    const float n = tanhf(g[2048 + j] + r * g[3072 + j]);
    const float h = (1.f - z) * n + z * h32[idx];
    h32[idx] = h;
    split2h(h, hA0[idx], hA1[idx]);
}

__global__ __launch_bounds__(256) void ew_t0_16(
    const float* __restrict__ gbuf, float* __restrict__ h32,
    _Float16* __restrict__ hA0, _Float16* __restrict__ hA1)
{
    const int idx = blockIdx.x * 256 + threadIdx.x;   // 0..524287
    const int b = idx >> 10, j = idx & 1023;
    const float* g = gbuf + (size_t)b * 6144;
    const float pr  = g[j]        + g[3072 + j];
    const float pz  = g[1024 + j] + g[4096 + j];
    const float r = 1.f / (1.f + expf(-pr));
    const float z = 1.f / (1.f + expf(-pz));
    const float n = tanhf(g[2048 + j] + r * g[5120 + j]);
    const float h = (1.f - z) * n + z * h32[idx];
    h32[idx] = h;
    split2h(h, hA0[idx], hA1[idx]);
}

// ---------------------------------------------------------------------------
// Prep kernels
// ---------------------------------------------------------------------------
__global__ __launch_bounds__(256) void transpose_wout(
    const float* __restrict__ W_out, float* __restrict__ WoutT)
{
    const int idx = blockIdx.x * 256 + threadIdx.x;   // < 1024*1024
    const int o = idx >> 10, c = idx & 1023;
    WoutT[(size_t)c * 1024 + o] = W_out[idx];
}

// Build Wbig (5120x1024) f16 2-plane split of 16*W from fp32 sources.
__global__ __launch_bounds__(256) void prep_w16(
    const float* __restrict__ wcomb,     // [3072][1024] fp32
    const float* __restrict__ W_hh,      // [3072][1024] fp32
    const float* __restrict__ W_out,     // [1024][1024] fp32
    _Float16* __restrict__ W0, _Float16* __restrict__ W1)
{
    const int idx = blockIdx.x * 256 + threadIdx.x;   // < 5120*1024
    const int row = idx >> 10, col = idx & 1023;
    float v;
    if (row < 2048)      v = wcomb[idx] + W_hh[idx];
    else if (row < 3072) v = wcomb[idx];
    else if (row < 4096) v = W_hh[(size_t)(row - 1024) * 1024 + col];
    else                 v = W_out[(size_t)(row - 4096) * 1024 + col];
    split2h(v * 16.0f, W0[idx], W1[idx]);
}

__global__ __launch_bounds__(256) void prep_bias(
    const float* __restrict__ W_ih,
    const float* __restrict__ b_ih, const float* __restrict__ b_hh,
    const float* __restrict__ b_out,
    float* __restrict__ bias_big)
{
    const int n = blockIdx.x * 256 + threadIdx.x;     // < 5120
    if (n >= 5120) return;
    float v;
    if (n < 3072) {
        float d = 0.f;
        for (int o = 0; o < 1024; ++o) d += W_ih[(size_t)n * 1026 + o] * b_out[o];
        v = b_ih[n] + d + (n < 2048 ? b_hh[n] : 0.f);
    } else if (n < 4096) v = b_hh[n - 1024];
    else                 v = b_out[n - 4096];
    bias_big[n] = v;
}

__global__ __launch_bounds__(256) void init_h16(
    const float* __restrict__ h0, float* __restrict__ h32,
    _Float16* __restrict__ hA0, _Float16* __restrict__ hA1)
{
    const int idx = blockIdx.x * 256 + threadIdx.x;   // < 524288
    const float hv = h0[idx];
    h32[idx] = hv;
    split2h(hv, hA0[idx], hA1[idx]);
}

// ===========================================================================
// fp32 vector GEMM (round-3 verified) — t=0, one-time W_comb, fallback.
// ===========================================================================
__global__ __launch_bounds__(256) void gemm_f32(
    const float* __restrict__ A, int lda,
    const float* __restrict__ Bm, int ldb,
    const float* __restrict__ bias,
    const float* __restrict__ act,
    float* __restrict__ dst, int dst_stride, int dst_coloff)
{
    __shared__ float As[16][64];
    __shared__ float Bs[16][64];
    const int t  = threadIdx.x;
    const int tx = t & 15, ty = t >> 4;
    const int row0 = blockIdx.y * 64, col0 = blockIdx.x * 64;
    const int lm = t >> 2;
    const int lk = (t & 3) * 4;
    float acc[4][4] = {};
    for (int kt = 0; kt < 64; ++kt) {
        const int kbase = kt * 16 + lk;
        const float* ap = A + (size_t)(row0 + lm) * lda + kbase;
        const float a0 = ap[0], a1 = ap[1], a2 = ap[2], a3 = ap[3];
        const float* bp = Bm + (size_t)(col0 + lm) * ldb + kbase;
        const float b0 = bp[0], b1 = bp[1], b2 = bp[2], b3 = bp[3];
        __syncthreads();
        As[lk + 0][lm] = a0;   As[lk + 1][lm] = a1;
        As[lk + 2][lm] = a2;   As[lk + 3][lm] = a3;
        Bs[lk + 0][lm] = b0;   Bs[lk + 1][lm] = b1;
        Bs[lk + 2][lm] = b2;   Bs[lk + 3][lm] = b3;
        __syncthreads();
#pragma unroll
        for (int kk = 0; kk < 16; ++kk) {
            const f32x4 a4 = *(const f32x4*)&As[kk][ty * 4];
            const f32x4 b4 = *(const f32x4*)&Bs[kk][tx * 4];
#pragma unroll
            for (int i = 0; i < 4; ++i)
#pragma unroll
                for (int j = 0; j < 4; ++j)
                    acc[i][j] += a4[i] * b4[j];
        }
    }
#pragma unroll
    for (int i = 0; i < 4; ++i) {
        const int row = row0 + ty * 4 + i;
        float a0 = 0.f, a1 = 0.f;
        if (act) { a0 = act[row * 2]; a1 = act[row * 2 + 1]; }
#pragma unroll
        for (int j = 0; j < 4; ++j) {
            const int col = col0 + tx * 4 + j;
            float v = acc[i][j] + (bias ? bias[col] : 0.f);
            if (act) v += a0 * Bm[(size_t)col * ldb + 1024]
                        + a1 * Bm[(size_t)col * ldb + 1025];
            dst[(size_t)row * dst_stride + dst_coloff + col] = v;
        }
    }
}

__global__ __launch_bounds__(256) void ew_gru32(
    const float* __restrict__ gbuf, float* __restrict__ h32)
{
    const int idx = blockIdx.x * 256 + threadIdx.x;
    const int b = idx >> 10, j = idx & 1023;
    const float* g = gbuf + (size_t)b * 6144;
    const float pr  = g[j]        + g[3072 + j];
    const float pz  = g[1024 + j] + g[4096 + j];
    const float r = 1.f / (1.f + expf(-pr));
    const float z = 1.f / (1.f + expf(-pz));
    const float n = tanhf(g[2048 + j] + r * g[5120 + j]);
    h32[idx] = (1.f - z) * n + z * h32[idx];
}

__global__ __launch_bounds__(256) void init_h(const float* __restrict__ h0,
                                              float* __restrict__ h32) {
    const int idx = blockIdx.x * 256 + threadIdx.x;
    h32[idx] = h0[idx];
}

// ---------------------------------------------------------------------------
extern "C" void kernel_launch(void* const* d_in, const int* in_sizes, int n_in,
                              void* d_out, int out_size, void* d_ws, size_t ws_size,
                              hipStream_t stream) {
    const float* enc     = (const float*)d_in[0];
    const float* actions = (const float*)d_in[1];   // [64][512][2]
    const float* h0      = (const float*)d_in[2];
    const float* W_ih    = (const float*)d_in[3];   // [3072][1026]
    const float* W_hh    = (const float*)d_in[4];   // [3072][1024]
    const float* b_ih    = (const float*)d_in[5];
    const float* b_hh    = (const float*)d_in[6];
    const float* W_out   = (const float*)d_in[7];   // [1024][1024]
    const float* b_out   = (const float*)d_in[8];
    float* out = (float*)d_out;                     // [64][512][1024]
    char* ws = (char*)d_ws;

    float* h32  = (float*)ws;                       // 2,097,152 B
    float* gbuf = (float*)(ws + 2097152);           // 12,582,912 -> 14,680,064

    const size_t NEED = 54546432;
    if (ws_size < NEED) {
        // ---------------- fp32 fallback (round-3 verified) ----------------
        init_h<<<2048, 256, 0, stream>>>(h0, h32);
        const float* e = enc;
        for (int t = 0; t < 64; ++t) {
            gemm_f32<<<dim3(48, 8), 256, 0, stream>>>(
                e, 1024, W_ih, 1026, b_ih, actions + (size_t)t * 1024, gbuf, 6144, 0);
            gemm_f32<<<dim3(48, 8), 256, 0, stream>>>(
                h32, 1024, W_hh, 1024, b_hh, nullptr, gbuf, 6144, 3072);
            ew_gru32<<<2048, 256, 0, stream>>>(gbuf, h32);
            float* ot = out + (size_t)t * 524288;
            gemm_f32<<<dim3(16, 8), 256, 0, stream>>>(
                h32, 1024, W_out, 1024, b_out, nullptr, ot, 1024, 0);
            e = ot;
        }
        return;
    }

    // ---------------- f16 2-plane MFMA path ----------------
    size_t off = 14680064;
    auto take = [&](size_t bytes) { char* p = ws + off; off += bytes; return p; };
    _Float16* W0   = (_Float16*)take(10485760);   // 5120x1024
    _Float16* W1   = (_Float16*)take(10485760);
    _Float16* hA0  = (_Float16*)take(1048576);    // 512x1024
    _Float16* hA1  = (_Float16*)take(1048576);
    float* WoutT   = (float*)take(4194304);       // 1024x1024 f32
    float* wcomb   = (float*)take(12582912);      // 3072x1024 f32
    float* bias_big= (float*)take(20480);         // 5120 f32
    // off == 54,546,432

    // One-time prep: W_comb = W_ih[:, :1024] @ W_out (fp32), W planes, bias.
    transpose_wout<<<4096, 256, 0, stream>>>(W_out, WoutT);
    gemm_f32<<<dim3(16, 48), 256, 0, stream>>>(
        W_ih, 1026, WoutT, 1024, nullptr, nullptr, wcomb, 1024, 0);
    prep_w16<<<20480, 256, 0, stream>>>(wcomb, W_hh, W_out, W0, W1);
    prep_bias<<<20, 256, 0, stream>>>(W_ih, b_ih, b_hh, b_out, bias_big);
    init_h16<<<2048, 256, 0, stream>>>(h0, h32, hA0, hA1);

    // t = 0 in fp32 (e = enc), then split h_1.
    gemm_f32<<<dim3(48, 8), 256, 0, stream>>>(
        enc, 1024, W_ih, 1026, b_ih, actions, gbuf, 6144, 0);
    gemm_f32<<<dim3(48, 8), 256, 0, stream>>>(
        h32, 1024, W_hh, 1024, b_hh, nullptr, gbuf, 6144, 3072);
    ew_t0_16<<<2048, 256, 0, stream>>>(gbuf, h32, hA0, hA1);

    // t = 1..63: one folded GEMM (gates_t + out_{t-1}) + ew.
    for (int t = 1; t < 64; ++t) {
        gemm_step16<<<320, 256, 0, stream>>>(hA0, hA1, W0, W1, gbuf,
                                             out + (size_t)(t - 1) * 524288,
                                             bias_big, W_ih,
                                             actions + (size_t)t * 1024, 0);
        ew_fold16<<<2048, 256, 0, stream>>>(gbuf, h32, hA0, hA1);
    }
    // out_63 = h_64 @ W_out.T + b_out
    gemm_step16<<<64, 256, 0, stream>>>(hA0, hA1, W0, W1, gbuf,
                                        out + (size_t)63 * 524288,
                                        bias_big, W_ih, actions, 4096);
}

// Round 10
// 3346.619 us; speedup vs baseline: 3.6522x; 1.7130x over previous
//
#include <hip/hip_runtime.h>
#include <stdint.h>
#include <stddef.h>

// RNNPredictorBurnin — round 10: coalesced staging (the r5..r9 cores loaded
// 16B/lane at 2KB stride -> ~64 transactions/instr; now lane l covers
// contiguous 1KB per instr, m97-style) + wcomb/t0 moved onto the f16 core.
// Math identical to r9: f16 2-plane scaled split, 3 terms (~2^-22),
// folded W_comb step GEMM, fp32 master h, fp32 fallback kept.

typedef _Float16 f16x8 __attribute__((ext_vector_type(8)));
typedef float f32x4  __attribute__((ext_vector_type(4)));

__device__ __forceinline__ void split2h(float v, _Float16& a, _Float16& b) {
    a = (_Float16)v;
    b = (_Float16)((v - (float)a) * 2048.0f);
}

__device__ __forceinline__ int swz(int row, int col) {   // LDS byte address
    return row * 128 + (col ^ ((row & 7) << 4));
}

// ---------------------------------------------------------------------------
// 3-term f16 GEMM core, 128x64 tile, K=1024 (48 iters: 16/segment).
// seg0: A0*B0 -> acc0 ; seg1: A0*B1 -> accL ; seg2: A1*B0 -> accL.
// Coalesced staging: instr j, lane l -> row base+j*8+(l>>3), byte (l&7)*16.
// 1-deep register prefetch; XOR-swizzled LDS (write & read).
// ---------------------------------------------------------------------------
__device__ __forceinline__ void load_chunk(
    const _Float16* __restrict__ A0, const _Float16* __restrict__ A1,
    const _Float16* __restrict__ B0, const _Float16* __restrict__ B1,
    int mrow0, int nrow0, int wid, int lr, int lc, int kt,
    f16x8 (&ra)[4], f16x8 (&rb)[2])
{
    const int seg = kt >> 4;
    const _Float16* Ab = (seg == 2) ? A1 : A0;
    const _Float16* Bb = (seg == 1) ? B1 : B0;
    const int koff = (kt & 15) * 128;
    const char* Abase = (const char*)Ab + koff + lc;
    const char* Bbase = (const char*)Bb + koff + lc;
#pragma unroll
    for (int j = 0; j < 4; ++j)
        ra[j] = *(const f16x8*)(Abase + (size_t)(mrow0 + wid * 32 + j * 8 + lr) * 2048);
#pragma unroll
    for (int j = 0; j < 2; ++j)
        rb[j] = *(const f16x8*)(Bbase + (size_t)(nrow0 + wid * 16 + j * 8 + lr) * 2048);
}

__device__ __forceinline__ void gemm_core16(
    const _Float16* __restrict__ A0, const _Float16* __restrict__ A1,
    const _Float16* __restrict__ B0, const _Float16* __restrict__ B1,
    int mrow0, int nrow0,
    char* ldsA, char* ldsB,
    f32x4 (&acc0)[4][2], f32x4 (&accL)[4][2])
{
    const int tid  = threadIdx.x;
    const int wid  = tid >> 6;
    const int lane = tid & 63;
    const int wr = wid >> 1, wc = wid & 1;
    const int l16 = lane & 15, lq = lane >> 4;
    const int lr = lane >> 3, lc = (lane & 7) << 4;
    const int sw = lc ^ (lr << 4);            // staged rows have row&7 == lr

    f16x8 pa[4], pb[2], na[4], nb[2];
    load_chunk(A0, A1, B0, B1, mrow0, nrow0, wid, lr, lc, 0, pa, pb);

    for (int kt = 0; kt < 48; ++kt) {
        if (kt < 47)
            load_chunk(A0, A1, B0, B1, mrow0, nrow0, wid, lr, lc, kt + 1, na, nb);
        __syncthreads();
#pragma unroll
        for (int j = 0; j < 4; ++j)
            *(f16x8*)(ldsA + (wid * 32 + j * 8 + lr) * 128 + sw) = pa[j];
#pragma unroll
        for (int j = 0; j < 2; ++j)
            *(f16x8*)(ldsB + (wid * 16 + j * 8 + lr) * 128 + sw) = pb[j];
        __syncthreads();

#pragma unroll
        for (int kk = 0; kk < 2; ++kk) {
            f16x8 af[4], bf[2];
            const int col = kk * 64 + lq * 16;
#pragma unroll
            for (int mi = 0; mi < 4; ++mi)
                af[mi] = *(const f16x8*)(ldsA + swz(wr * 64 + mi * 16 + l16, col));
#pragma unroll
            for (int ni = 0; ni < 2; ++ni)
                bf[ni] = *(const f16x8*)(ldsB + swz(wc * 32 + ni * 16 + l16, col));
            if (kt < 16) {
#pragma unroll
                for (int mi = 0; mi < 4; ++mi)
#pragma unroll
                    for (int ni = 0; ni < 2; ++ni)
                        acc0[mi][ni] = __builtin_amdgcn_mfma_f32_16x16x32_f16(
                            af[mi], bf[ni], acc0[mi][ni], 0, 0, 0);
            } else {
#pragma unroll
                for (int mi = 0; mi < 4; ++mi)
#pragma unroll
                    for (int ni = 0; ni < 2; ++ni)
                        accL[mi][ni] = __builtin_amdgcn_mfma_f32_16x16x32_f16(
                            af[mi], bf[ni], accL[mi][ni], 0, 0, 0);
            }
        }
        if (kt < 47) {
#pragma unroll
            for (int j = 0; j < 4; ++j) pa[j] = na[j];
#pragma unroll
            for (int j = 0; j < 2; ++j) pb[j] = nb[j];
        }
    }
}

// ---------------------------------------------------------------------------
// Folded step GEMM. A = h (2 f16 planes, unscaled). B = Wbig*16 (2 planes):
// [0,2048) rz ; [2048,3072) gi_n ; [3072,4096) gh_n ; [4096,5120) W_out.
// Steps: 320 blocks (4 mt x 80 nt, XCD-contiguous). Final: 64 blocks.
// ---------------------------------------------------------------------------
__global__ __launch_bounds__(256) void gemm_step16(
    const _Float16* __restrict__ hA0, const _Float16* __restrict__ hA1,
    const _Float16* __restrict__ W0, const _Float16* __restrict__ W1,
    float* __restrict__ gbuf, float* __restrict__ outp,
    const float* __restrict__ bias_big,
    const float* __restrict__ W_ih,      // fp32 [3072][1026], action cols
    const float* __restrict__ act,       // actions + t*1024
    int col_base)
{
    __shared__ alignas(16) char lds[24576];   // A 16KB + B 8KB
    const int bid = blockIdx.x;
    int mt, nt;
    if (col_base) { mt = bid & 3; nt = bid >> 2; }            // 64 blocks
    else { const int xcd = bid & 7, loc = bid >> 3;           // 320 blocks
           mt = loc & 3; nt = xcd * 10 + (loc >> 2); }        // nt 0..79
    f32x4 acc0[4][2] = {}, accL[4][2] = {};
    gemm_core16(hA0, hA1, W0, W1, mt * 128, col_base + nt * 64,
                lds, lds + 16384, acc0, accL);

    const int lane = threadIdx.x & 63, wid = threadIdx.x >> 6;
    const int wr = wid >> 1, wc = wid & 1, l16 = lane & 15, lq = lane >> 4;
#pragma unroll
    for (int ni = 0; ni < 2; ++ni) {
        const int n = col_base + nt * 64 + wc * 32 + ni * 16 + l16;
        const float bias = bias_big[n];
        float w0 = 0.f, w1 = 0.f;
        if (n < 3072) { w0 = W_ih[(size_t)n * 1026 + 1024];
                        w1 = W_ih[(size_t)n * 1026 + 1025]; }
#pragma unroll
        for (int mi = 0; mi < 4; ++mi) {
#pragma unroll
            for (int r = 0; r < 4; ++r) {
                const int brow = mt * 128 + wr * 64 + mi * 16 + lq * 4 + r;
                const float dot = (acc0[mi][ni][r] + accL[mi][ni][r] * (1.f/2048.f))
                                  * (1.f/16.f);
                const float v = dot + bias
                              + act[brow * 2] * w0 + act[brow * 2 + 1] * w1;
                if (n < 4096) gbuf[(size_t)brow * 4096 + n] = v;
                else          outp[(size_t)brow * 1024 + (n - 4096)] = v;
            }
        }
    }
}

// ---------------------------------------------------------------------------
// t=0 GEMM on the f16 core: nt<48 -> gi = enc @ Wih^T ; nt>=48 -> gh = h0 @ Whh^T.
// gbuf stride 6144 = [gi 3072 | gh 3072]. 384 blocks (4 mt x 96 nt).
// ---------------------------------------------------------------------------
__global__ __launch_bounds__(256) void gemm_t0_16(
    const _Float16* __restrict__ e0, const _Float16* __restrict__ e1,
    const _Float16* __restrict__ hA0, const _Float16* __restrict__ hA1,
    const _Float16* __restrict__ Wih0, const _Float16* __restrict__ Wih1,
    const _Float16* __restrict__ Whh0, const _Float16* __restrict__ Whh1,
    const float* __restrict__ W_ih,
    const float* __restrict__ b_ih, const float* __restrict__ b_hh,
    const float* __restrict__ act,       // actions t=0
    float* __restrict__ gbuf)
{
    __shared__ alignas(16) char lds[24576];
    const int bid = blockIdx.x;
    const int mt = bid & 3, nt = bid >> 2;      // nt 0..95
    const _Float16 *A0, *A1, *B0, *B1; int nr0;
    if (nt < 48) { A0 = e0;  A1 = e1;  B0 = Wih0; B1 = Wih1; nr0 = nt * 64; }
    else         { A0 = hA0; A1 = hA1; B0 = Whh0; B1 = Whh1; nr0 = (nt - 48) * 64; }
    f32x4 acc0[4][2] = {}, accL[4][2] = {};
    gemm_core16(A0, A1, B0, B1, mt * 128, nr0, lds, lds + 16384, acc0, accL);

    const int lane = threadIdx.x & 63, wid = threadIdx.x >> 6;
    const int wr = wid >> 1, wc = wid & 1, l16 = lane & 15, lq = lane >> 4;
#pragma unroll
    for (int ni = 0; ni < 2; ++ni) {
        const int ncol = nt * 64 + wc * 32 + ni * 16 + l16;   // 0..6143
        float bias, w0 = 0.f, w1 = 0.f;
        if (ncol < 3072) {
            bias = b_ih[ncol];
            w0 = W_ih[(size_t)ncol * 1026 + 1024];
            w1 = W_ih[(size_t)ncol * 1026 + 1025];
        } else bias = b_hh[ncol - 3072];
#pragma unroll
        for (int mi = 0; mi < 4; ++mi) {
#pragma unroll
            for (int r = 0; r < 4; ++r) {
                const int brow = mt * 128 + wr * 64 + mi * 16 + lq * 4 + r;
                const float dot = (acc0[mi][ni][r] + accL[mi][ni][r] * (1.f/2048.f))
                                  * (1.f/16.f);
                const float v = dot + bias
                              + act[brow * 2] * w0 + act[brow * 2 + 1] * w1;
                gbuf[(size_t)brow * 6144 + ncol] = v;
            }
        }
    }
}

// ---------------------------------------------------------------------------
// W_comb = W_ih[:, :1024] @ W_out on the f16 core (A=Wih*16, B=WoutT*16 ->
// /256). rows<2048 add W_hh; result *16 split -> Wbig planes rows 0..3071.
// 384 blocks (24 mt x 16 nt).
// ---------------------------------------------------------------------------
__global__ __launch_bounds__(256) void gemm_wcomb16(
    const _Float16* __restrict__ Wih0, const _Float16* __restrict__ Wih1,
    const _Float16* __restrict__ WoT0, const _Float16* __restrict__ WoT1,
    const float* __restrict__ W_hh,
    _Float16* __restrict__ W0, _Float16* __restrict__ W1)
{
    __shared__ alignas(16) char lds[24576];
    const int bid = blockIdx.x;
    const int mt = bid >> 4, nt = bid & 15;
    f32x4 acc0[4][2] = {}, accL[4][2] = {};
    gemm_core16(Wih0, Wih1, WoT0, WoT1, mt * 128, nt * 64,
                lds, lds + 16384, acc0, accL);

    const int lane = threadIdx.x & 63, wid = threadIdx.x >> 6;
    const int wr = wid >> 1, wc = wid & 1, l16 = lane & 15, lq = lane >> 4;
#pragma unroll
    for (int ni = 0; ni < 2; ++ni) {
        const int c = nt * 64 + wc * 32 + ni * 16 + l16;       // 0..1023
#pragma unroll
        for (int mi = 0; mi < 4; ++mi) {
#pragma unroll
            for (int r = 0; r < 4; ++r) {
                const int i = mt * 128 + wr * 64 + mi * 16 + lq * 4 + r;  // 0..3071
                float v = (acc0[mi][ni][r] + accL[mi][ni][r] * (1.f/2048.f))
                          * (1.f/256.f);
                if (i < 2048) v += W_hh[(size_t)i * 1024 + c];
                _Float16 a, b; split2h(v * 16.0f, a, b);
                W0[(size_t)i * 1024 + c] = a;
                W1[(size_t)i * 1024 + c] = b;
            }
        }
    }
}

// ---------------------------------------------------------------------------
// GRU updates (fp32 master h + f16 planes)
// ---------------------------------------------------------------------------
__global__ __launch_bounds__(256) void ew_fold16(
    const float* __restrict__ gbuf, float* __restrict__ h32,
    _Float16* __restrict__ hA0, _Float16* __restrict__ hA1)
{
    const int idx = blockIdx.x * 256 + threadIdx.x;   // 0..524287
    const int b = idx >> 10, j = idx & 1023;
    const float* g = gbuf + (size_t)b * 4096;
    const float r = 1.f / (1.f + expf(-g[j]));
    const float z = 1.f / (1.f + expf(-g[1024 + j]));
    const float n = tanhf(g[2048 + j] + r * g[3072 + j]);
    const float h = (1.f - z) * n + z * h32[idx];
    h32[idx] = h;
    split2h(h, hA0[idx], hA1[idx]);
}

__global__ __launch_bounds__(256) void ew_t0_16(
    const float* __restrict__ gbuf, float* __restrict__ h32,
    _Float16* __restrict__ hA0, _Float16* __restrict__ hA1)
{
    const int idx = blockIdx.x * 256 + threadIdx.x;   // 0..524287
    const int b = idx >> 10, j = idx & 1023;
    const float* g = gbuf + (size_t)b * 6144;
    const float pr  = g[j]        + g[3072 + j];
    const float pz  = g[1024 + j] + g[4096 + j];
    const float r = 1.f / (1.f + expf(-pr));
    const float z = 1.f / (1.f + expf(-pz));
    const float n = tanhf(g[2048 + j] + r * g[5120 + j]);
    const float h = (1.f - z) * n + z * h32[idx];
    h32[idx] = h;
    split2h(h, hA0[idx], hA1[idx]);
}

// ---------------------------------------------------------------------------
// Prep kernels
// ---------------------------------------------------------------------------
__global__ __launch_bounds__(256) void prep_w16(
    const float* __restrict__ W_ih, const float* __restrict__ W_hh,
    const float* __restrict__ W_out,
    _Float16* __restrict__ Wih0, _Float16* __restrict__ Wih1,
    _Float16* __restrict__ Whh0, _Float16* __restrict__ Whh1,
    _Float16* __restrict__ WoT0, _Float16* __restrict__ WoT1,
    _Float16* __restrict__ W0,   _Float16* __restrict__ W1)
{
    const int idx = blockIdx.x * 256 + threadIdx.x;   // < 3072*1024
    const int n = idx >> 10, k = idx & 1023;
    _Float16 a, b;
    split2h(W_ih[(size_t)n * 1026 + k] * 16.0f, a, b);
    Wih0[idx] = a; Wih1[idx] = b;
    split2h(W_hh[idx] * 16.0f, a, b);
    Whh0[idx] = a; Whh1[idx] = b;
    if (n >= 2048) {                                  // gh_n rows of Wbig
        W0[(size_t)(n + 1024) * 1024 + k] = a;
        W1[(size_t)(n + 1024) * 1024 + k] = b;
    }
    if (n < 1024) {                                   // W_out rows + transpose
        split2h(W_out[idx] * 16.0f, a, b);
        W0[(size_t)(4096 + n) * 1024 + k] = a;
        W1[(size_t)(4096 + n) * 1024 + k] = b;
        WoT0[(size_t)k * 1024 + n] = a;
        WoT1[(size_t)k * 1024 + n] = b;
    }
}

__global__ __launch_bounds__(256) void prep_m16(
    const float* __restrict__ enc, const float* __restrict__ h0,
    const float* __restrict__ W_ih,
    const float* __restrict__ b_ih, const float* __restrict__ b_hh,
    const float* __restrict__ b_out,
    _Float16* __restrict__ e0, _Float16* __restrict__ e1,
    _Float16* __restrict__ hA0, _Float16* __restrict__ hA1,
    float* __restrict__ h32, float* __restrict__ bias_big)
{
    const int idx = blockIdx.x * 256 + threadIdx.x;
    if (idx < 524288) {
        split2h(enc[idx], e0[idx], e1[idx]);
        const float hv = h0[idx];
        h32[idx] = hv;
        split2h(hv, hA0[idx], hA1[idx]);
    } else if (idx < 524288 + 5120) {
        const int nn = idx - 524288;
        float v;
        if (nn < 3072) {
            float d = 0.f;
            for (int o = 0; o < 1024; ++o) d += W_ih[(size_t)nn * 1026 + o] * b_out[o];
            v = b_ih[nn] + d + (nn < 2048 ? b_hh[nn] : 0.f);
        } else if (nn < 4096) v = b_hh[nn - 1024];
        else                  v = b_out[nn - 4096];
        bias_big[nn] = v;
    }
}

// ===========================================================================
// fp32 fallback (round-3 verified) for small ws_size.
// ===========================================================================
__global__ __launch_bounds__(256) void gemm_f32(
    const float* __restrict__ A, int lda,
    const float* __restrict__ Bm, int ldb,
    const float* __restrict__ bias,
    const float* __restrict__ act,
    float* __restrict__ dst, int dst_stride, int dst_coloff)
{
    __shared__ float As[16][64];
    __shared__ float Bs[16][64];
    const int t  = threadIdx.x;
    const int tx = t & 15, ty = t >> 4;
    const int row0 = blockIdx.y * 64, col0 = blockIdx.x * 64;
    const int lm = t >> 2;
    const int lk = (t & 3) * 4;
    float acc[4][4] = {};
    for (int kt = 0; kt < 64; ++kt) {
        const int kbase = kt * 16 + lk;
        const float* ap = A + (size_t)(row0 + lm) * lda + kbase;
        const float a0 = ap[0], a1 = ap[1], a2 = ap[2], a3 = ap[3];
        const float* bp = Bm + (size_t)(col0 + lm) * ldb + kbase;
        const float b0 = bp[0], b1 = bp[1], b2 = bp[2], b3 = bp[3];
        __syncthreads();
        As[lk + 0][lm] = a0;   As[lk + 1][lm] = a1;
        As[lk + 2][lm] = a2;   As[lk + 3][lm] = a3;
        Bs[lk + 0][lm] = b0;   Bs[lk + 1][lm] = b1;
        Bs[lk + 2][lm] = b2;   Bs[lk + 3][lm] = b3;
        __syncthreads();
#pragma unroll
        for (int kk = 0; kk < 16; ++kk) {
            const f32x4 a4 = *(const f32x4*)&As[kk][ty * 4];
            const f32x4 b4 = *(const f32x4*)&Bs[kk][tx * 4];
#pragma unroll
            for (int i = 0; i < 4; ++i)
#pragma unroll
                for (int j = 0; j < 4; ++j)
                    acc[i][j] += a4[i] * b4[j];
        }
    }
#pragma unroll
    for (int i = 0; i < 4; ++i) {
        const int row = row0 + ty * 4 + i;
        float a0 = 0.f, a1 = 0.f;
        if (act) { a0 = act[row * 2]; a1 = act[row * 2 + 1]; }
#pragma unroll
        for (int j = 0; j < 4; ++j) {
            const int col = col0 + tx * 4 + j;
            float v = acc[i][j] + (bias ? bias[col] : 0.f);
            if (act) v += a0 * Bm[(size_t)col * ldb + 1024]
                        + a1 * Bm[(size_t)col * ldb + 1025];
            dst[(size_t)row * dst_stride + dst_coloff + col] = v;
        }
    }
}

__global__ __launch_bounds__(256) void ew_gru32(
    const float* __restrict__ gbuf, float* __restrict__ h32)
{
    const int idx = blockIdx.x * 256 + threadIdx.x;
    const int b = idx >> 10, j = idx & 1023;
    const float* g = gbuf + (size_t)b * 6144;
    const float pr  = g[j]        + g[3072 + j];
    const float pz  = g[1024 + j] + g[4096 + j];
    const float r = 1.f / (1.f + expf(-pr));
    const float z = 1.f / (1.f + expf(-pz));
    const float n = tanhf(g[2048 + j] + r * g[5120 + j]);
    h32[idx] = (1.f - z) * n + z * h32[idx];
}

__global__ __launch_bounds__(256) void init_h(const float* __restrict__ h0,
                                              float* __restrict__ h32) {
    const int idx = blockIdx.x * 256 + threadIdx.x;
    h32[idx] = h0[idx];
}

// ---------------------------------------------------------------------------
extern "C" void kernel_launch(void* const* d_in, const int* in_sizes, int n_in,
                              void* d_out, int out_size, void* d_ws, size_t ws_size,
                              hipStream_t stream) {
    const float* enc     = (const float*)d_in[0];
    const float* actions = (const float*)d_in[1];   // [64][512][2]
    const float* h0      = (const float*)d_in[2];
    const float* W_ih    = (const float*)d_in[3];   // [3072][1026]
    const float* W_hh    = (const float*)d_in[4];   // [3072][1024]
    const float* b_ih    = (const float*)d_in[5];
    const float* b_hh    = (const float*)d_in[6];
    const float* W_out   = (const float*)d_in[7];   // [1024][1024]
    const float* b_out   = (const float*)d_in[8];
    float* out = (float*)d_out;                     // [64][512][1024]
    char* ws = (char*)d_ws;

    float* h32  = (float*)ws;                       // 2,097,152 B
    float* gbuf = (float*)(ws + 2097152);           // 12,582,912 -> 14,680,064

    const size_t NEED = 69226496;                   // == r7's proven-available
    if (ws_size < NEED) {
        // ---------------- fp32 fallback (round-3 verified) ----------------
        init_h<<<2048, 256, 0, stream>>>(h0, h32);
        const float* e = enc;
        for (int t = 0; t < 64; ++t) {
            gemm_f32<<<dim3(48, 8), 256, 0, stream>>>(
                e, 1024, W_ih, 1026, b_ih, actions + (size_t)t * 1024, gbuf, 6144, 0);
            gemm_f32<<<dim3(48, 8), 256, 0, stream>>>(
                h32, 1024, W_hh, 1024, b_hh, nullptr, gbuf, 6144, 3072);
            ew_gru32<<<2048, 256, 0, stream>>>(gbuf, h32);
            float* ot = out + (size_t)t * 524288;
            gemm_f32<<<dim3(16, 8), 256, 0, stream>>>(
                h32, 1024, W_out, 1024, b_out, nullptr, ot, 1024, 0);
            e = ot;
        }
        return;
    }

    // ---------------- f16 2-plane MFMA path ----------------
    size_t off = 14680064;
    auto take = [&](size_t bytes) { char* p = ws + off; off += bytes; return p; };
    _Float16* W0   = (_Float16*)take(10485760);   // Wbig planes 5120x1024
    _Float16* W1   = (_Float16*)take(10485760);
    _Float16* Wih0 = (_Float16*)take(6291456);    // 3072x1024
    _Float16* Wih1 = (_Float16*)take(6291456);
    _Float16* Whh0 = (_Float16*)take(6291456);
    _Float16* Whh1 = (_Float16*)take(6291456);
    _Float16* WoT0 = (_Float16*)take(2097152);    // 1024x1024
    _Float16* WoT1 = (_Float16*)take(2097152);
    _Float16* e0   = (_Float16*)take(1048576);    // 512x1024
    _Float16* e1   = (_Float16*)take(1048576);
    _Float16* hA0  = (_Float16*)take(1048576);
    _Float16* hA1  = (_Float16*)take(1048576);
    float* bias_big= (float*)take(20480);         // 5120 f32
    // off == 69,226,496

    prep_w16<<<12288, 256, 0, stream>>>(W_ih, W_hh, W_out,
        Wih0, Wih1, Whh0, Whh1, WoT0, WoT1, W0, W1);
    prep_m16<<<2068, 256, 0, stream>>>(enc, h0, W_ih, b_ih, b_hh, b_out,
        e0, e1, hA0, hA1, h32, bias_big);
    gemm_wcomb16<<<384, 256, 0, stream>>>(Wih0, Wih1, WoT0, WoT1, W_hh, W0, W1);

    // t = 0 (e = enc), then h_1.
    gemm_t0_16<<<384, 256, 0, stream>>>(e0, e1, hA0, hA1,
        Wih0, Wih1, Whh0, Whh1, W_ih, b_ih, b_hh, actions, gbuf);
    ew_t0_16<<<2048, 256, 0, stream>>>(gbuf, h32, hA0, hA1);

    // t = 1..63: one folded GEMM (gates_t + out_{t-1}) + ew.
    for (int t = 1; t < 64; ++t) {
        gemm_step16<<<320, 256, 0, stream>>>(hA0, hA1, W0, W1, gbuf,
                                             out + (size_t)(t - 1) * 524288,
                                             bias_big, W_ih,
                                             actions + (size_t)t * 1024, 0);
        ew_fold16<<<2048, 256, 0, stream>>>(gbuf, h32, hA0, hA1);
    }
    // out_63 = h_64 @ W_out.T + b_out
    gemm_step16<<<64, 256, 0, stream>>>(hA0, hA1, W0, W1, gbuf,
                                        out + (size_t)63 * 524288,
                                        bias_big, W_ih, actions, 4096);
}

// Round 11
// 3049.083 us; speedup vs baseline: 4.0086x; 1.0976x over previous
//
#include <hip/hip_runtime.h>
#include <stdint.h>
#include <stddef.h>

// RNNPredictorBurnin — round 11: K-tile-major core (48 MFMA/barrier-pair,
// A staged once) + gate-interleaved Wbig + ew fused into the GEMM epilogue
// (shfl-gather of r/z/ni/nh in 4-lane groups). h planes double-buffered.
// Math identical to r10: f16 2-plane scaled split, 3 terms (~2^-22).

typedef _Float16 f16x8 __attribute__((ext_vector_type(8)));
typedef float f32x4  __attribute__((ext_vector_type(4)));

__device__ __forceinline__ void split2h(float v, _Float16& a, _Float16& b) {
    a = (_Float16)v;
    b = (_Float16)((v - (float)a) * 2048.0f);
}

__device__ __forceinline__ int swz(int row, int col) {   // LDS byte address
    return row * 128 + (col ^ ((row & 7) << 4));
}

// ---------------------------------------------------------------------------
// K-tile-major 3-term f16 core, 128x64 tile, K=1024, 16 outer iters.
// Per kt: stage A0,A1 (128x128B each) + B0,B1 (64x128B each) into LDS
// (48KB, regions 0/16K/32K/40K), then 2 kk passes x {A0B0->acc0,
// A0B1->accL, A1B0->accL}. 1-deep register prefetch, XOR-swizzled LDS.
// ---------------------------------------------------------------------------
__device__ __forceinline__ void stage_regs(
    const _Float16* __restrict__ A0, const _Float16* __restrict__ A1,
    const _Float16* __restrict__ B0, const _Float16* __restrict__ B1,
    int mrow0, int nrow0, int wid, int lr, int lc, int kt,
    f16x8 (&ra0)[4], f16x8 (&ra1)[4], f16x8 (&rb0)[2], f16x8 (&rb1)[2])
{
    const int koff = kt * 128 + lc;
    const char* a0 = (const char*)A0 + koff;
    const char* a1 = (const char*)A1 + koff;
    const char* b0 = (const char*)B0 + koff;
    const char* b1 = (const char*)B1 + koff;
#pragma unroll
    for (int j = 0; j < 4; ++j) {
        const size_t ro = (size_t)(mrow0 + wid * 32 + j * 8 + lr) * 2048;
        ra0[j] = *(const f16x8*)(a0 + ro);
        ra1[j] = *(const f16x8*)(a1 + ro);
    }
#pragma unroll
    for (int j = 0; j < 2; ++j) {
        const size_t ro = (size_t)(nrow0 + wid * 16 + j * 8 + lr) * 2048;
        rb0[j] = *(const f16x8*)(b0 + ro);
        rb1[j] = *(const f16x8*)(b1 + ro);
    }
}

__device__ __forceinline__ void gemm_core3t(
    const _Float16* __restrict__ A0, const _Float16* __restrict__ A1,
    const _Float16* __restrict__ B0, const _Float16* __restrict__ B1,
    int mrow0, int nrow0, char* lds,
    f32x4 (&acc0)[4][2], f32x4 (&accL)[4][2])
{
    const int tid  = threadIdx.x;
    const int wid  = tid >> 6;
    const int lane = tid & 63;
    const int wr = wid >> 1, wc = wid & 1;
    const int l16 = lane & 15, lq = lane >> 4;
    const int lr = lane >> 3, lc = (lane & 7) << 4;
    const int sw = lc ^ (lr << 4);           // staged rows: row&7 == lr

    f16x8 pa0[4], pa1[4], pb0[2], pb1[2];
    f16x8 na0[4], na1[4], nb0[2], nb1[2];
    stage_regs(A0, A1, B0, B1, mrow0, nrow0, wid, lr, lc, 0, pa0, pa1, pb0, pb1);

    for (int kt = 0; kt < 16; ++kt) {
        if (kt < 15)
            stage_regs(A0, A1, B0, B1, mrow0, nrow0, wid, lr, lc, kt + 1,
                       na0, na1, nb0, nb1);
        __syncthreads();
#pragma unroll
        for (int j = 0; j < 4; ++j) {
            const int ro = (wid * 32 + j * 8 + lr) * 128 + sw;
            *(f16x8*)(lds + ro)         = pa0[j];
            *(f16x8*)(lds + 16384 + ro) = pa1[j];
        }
#pragma unroll
        for (int j = 0; j < 2; ++j) {
            const int ro = (wid * 16 + j * 8 + lr) * 128 + sw;
            *(f16x8*)(lds + 32768 + ro) = pb0[j];
            *(f16x8*)(lds + 40960 + ro) = pb1[j];
        }
        __syncthreads();

#pragma unroll
        for (int kk = 0; kk < 2; ++kk) {
            const int col = kk * 64 + lq * 16;
            f16x8 af0[4], af1[4], bf0[2], bf1[2];
#pragma unroll
            for (int mi = 0; mi < 4; ++mi) {
                const int ad = swz(wr * 64 + mi * 16 + l16, col);
                af0[mi] = *(const f16x8*)(lds + ad);
                af1[mi] = *(const f16x8*)(lds + 16384 + ad);
            }
#pragma unroll
            for (int ni = 0; ni < 2; ++ni) {
                const int bd = swz(wc * 32 + ni * 16 + l16, col);
                bf0[ni] = *(const f16x8*)(lds + 32768 + bd);
                bf1[ni] = *(const f16x8*)(lds + 40960 + bd);
            }
#pragma unroll
            for (int mi = 0; mi < 4; ++mi)
#pragma unroll
                for (int ni = 0; ni < 2; ++ni)
                    acc0[mi][ni] = __builtin_amdgcn_mfma_f32_16x16x32_f16(
                        af0[mi], bf0[ni], acc0[mi][ni], 0, 0, 0);
#pragma unroll
            for (int mi = 0; mi < 4; ++mi)
#pragma unroll
                for (int ni = 0; ni < 2; ++ni)
                    accL[mi][ni] = __builtin_amdgcn_mfma_f32_16x16x32_f16(
                        af0[mi], bf1[ni], accL[mi][ni], 0, 0, 0);
#pragma unroll
            for (int mi = 0; mi < 4; ++mi)
#pragma unroll
                for (int ni = 0; ni < 2; ++ni)
                    accL[mi][ni] = __builtin_amdgcn_mfma_f32_16x16x32_f16(
                        af1[mi], bf0[ni], accL[mi][ni], 0, 0, 0);
        }
        if (kt < 15) {
#pragma unroll
            for (int j = 0; j < 4; ++j) { pa0[j] = na0[j]; pa1[j] = na1[j]; }
#pragma unroll
            for (int j = 0; j < 2; ++j) { pb0[j] = nb0[j]; pb1[j] = nb1[j]; }
        }
    }
}

// ---------------------------------------------------------------------------
// Fused step kernel. A = h_t planes. B = Wbig*16 planes, GATE-INTERLEAVED:
// row 4u+g (g: 0=r,1=z,2=gi_n,3=gh_n) for u<1024; rows [4096,5120) = W_out.
// nt<64: gate tile -> shfl-gather r/z/ni/nh per (row,unit), compute h_{t+1},
//        write h32 + f16 planes (double-buffered). nt>=64: out_{t-1} tile.
// Steps: grid 320 (nt_base=0, XCD-contiguous). Final out-only: grid 64,
// nt_base=64.
// ---------------------------------------------------------------------------
__global__ __launch_bounds__(256) void gemm_step_fused(
    const _Float16* __restrict__ hc0, const _Float16* __restrict__ hc1,
    const _Float16* __restrict__ W0,  const _Float16* __restrict__ W1,
    _Float16* __restrict__ hn0, _Float16* __restrict__ hn1,
    float* __restrict__ h32,
    float* __restrict__ outp,
    const float* __restrict__ bias_big,
    const float* __restrict__ W_ih,
    const float* __restrict__ act,
    int nt_base)
{
    __shared__ alignas(16) char lds[49152];
    int mt, nt;
    if (nt_base) { mt = blockIdx.x & 3; nt = nt_base + (blockIdx.x >> 2); }
    else { const int xcd = blockIdx.x & 7, loc = blockIdx.x >> 3;
           mt = loc & 3; nt = xcd * 10 + (loc >> 2); }       // nt 0..79
    const int nrow0 = (nt < 64) ? nt * 64 : 4096 + (nt - 64) * 64;
    f32x4 acc0[4][2] = {}, accL[4][2] = {};
    gemm_core3t(hc0, hc1, W0, W1, mt * 128, nrow0, lds, acc0, accL);

    const int lane = threadIdx.x & 63, wid = threadIdx.x >> 6;
    const int wr = wid >> 1, wc = wid & 1, l16 = lane & 15, lq = lane >> 4;

    if (nt >= 64) {                          // ---- out_{t-1} tile ----
#pragma unroll
        for (int ni = 0; ni < 2; ++ni) {
            const int oc = (nt - 64) * 64 + wc * 32 + ni * 16 + l16;
            const float bias = bias_big[4096 + oc];
#pragma unroll
            for (int mi = 0; mi < 4; ++mi)
#pragma unroll
                for (int r = 0; r < 4; ++r) {
                    const int brow = mt * 128 + wr * 64 + mi * 16 + lq * 4 + r;
                    const float v = (acc0[mi][ni][r]
                                   + accL[mi][ni][r] * (1.f/2048.f)) * (1.f/16.f)
                                  + bias;
                    outp[(size_t)brow * 1024 + oc] = v;
                }
        }
        return;
    }

    // ---- gate tile: fused GRU update ----
    const int gate = lane & 3;               // == (col & 3) for this lane
#pragma unroll
    for (int ni = 0; ni < 2; ++ni) {
        const int c = nt * 64 + wc * 32 + ni * 16 + l16;   // 0..4095
        const int u = c >> 2;
        const int orig_n = gate * 1024 + u;                // <3072 for gate<3
        const float bias = bias_big[orig_n];
        float w0 = 0.f, w1 = 0.f;
        if (gate < 3) { w0 = W_ih[(size_t)orig_n * 1026 + 1024];
                        w1 = W_ih[(size_t)orig_n * 1026 + 1025]; }
#pragma unroll
        for (int mi = 0; mi < 4; ++mi) {
#pragma unroll
            for (int r = 0; r < 4; ++r) {
                const int brow = mt * 128 + wr * 64 + mi * 16 + lq * 4 + r;
                const float v = (acc0[mi][ni][r]
                               + accL[mi][ni][r] * (1.f/2048.f)) * (1.f/16.f)
                              + bias
                              + act[brow * 2] * w0 + act[brow * 2 + 1] * w1;
                const float o1 = __shfl_xor(v, 1);
                const float o2 = __shfl_xor(v, 2);
                const float o3 = __shfl_xor(v, 3);
                if (gate == 0) {
                    // v=pr, o1=pz, o2=pni, o3=pnh
                    const float rr = 1.f / (1.f + expf(-v));
                    const float zz = 1.f / (1.f + expf(-o1));
                    const float nn = tanhf(o2 + rr * o3);
                    const size_t o = (size_t)brow * 1024 + u;
                    const float hnew = (1.f - zz) * nn + zz * h32[o];
                    h32[o] = hnew;
                    _Float16 a, b; split2h(hnew, a, b);
                    hn0[o] = a; hn1[o] = b;
                }
            }
        }
    }
}

// ---------------------------------------------------------------------------
// t=0 GEMM: nt<48 -> gi = enc @ Wih^T ; nt>=48 -> gh = h0 @ Whh^T.
// gbuf stride 6144. 384 blocks (4 mt x 96 nt).
// ---------------------------------------------------------------------------
__global__ __launch_bounds__(256) void gemm_t0_16(
    const _Float16* __restrict__ e0, const _Float16* __restrict__ e1,
    const _Float16* __restrict__ hA0, const _Float16* __restrict__ hA1,
    const _Float16* __restrict__ Wih0, const _Float16* __restrict__ Wih1,
    const _Float16* __restrict__ Whh0, const _Float16* __restrict__ Whh1,
    const float* __restrict__ W_ih,
    const float* __restrict__ b_ih, const float* __restrict__ b_hh,
    const float* __restrict__ act,
    float* __restrict__ gbuf)
{
    __shared__ alignas(16) char lds[49152];
    const int bid = blockIdx.x;
    const int mt = bid & 3, nt = bid >> 2;      // nt 0..95
    const _Float16 *A0, *A1, *B0, *B1; int nr0;
    if (nt < 48) { A0 = e0;  A1 = e1;  B0 = Wih0; B1 = Wih1; nr0 = nt * 64; }
    else         { A0 = hA0; A1 = hA1; B0 = Whh0; B1 = Whh1; nr0 = (nt - 48) * 64; }
    f32x4 acc0[4][2] = {}, accL[4][2] = {};
    gemm_core3t(A0, A1, B0, B1, mt * 128, nr0, lds, acc0, accL);

    const int lane = threadIdx.x & 63, wid = threadIdx.x >> 6;
    const int wr = wid >> 1, wc = wid & 1, l16 = lane & 15, lq = lane >> 4;
#pragma unroll
    for (int ni = 0; ni < 2; ++ni) {
        const int ncol = nt * 64 + wc * 32 + ni * 16 + l16;   // 0..6143
        float bias, w0 = 0.f, w1 = 0.f;
        if (ncol < 3072) {
            bias = b_ih[ncol];
            w0 = W_ih[(size_t)ncol * 1026 + 1024];
            w1 = W_ih[(size_t)ncol * 1026 + 1025];
        } else bias = b_hh[ncol - 3072];
#pragma unroll
        for (int mi = 0; mi < 4; ++mi)
#pragma unroll
            for (int r = 0; r < 4; ++r) {
                const int brow = mt * 128 + wr * 64 + mi * 16 + lq * 4 + r;
                const float v = (acc0[mi][ni][r]
                               + accL[mi][ni][r] * (1.f/2048.f)) * (1.f/16.f)
                              + bias
                              + act[brow * 2] * w0 + act[brow * 2 + 1] * w1;
                gbuf[(size_t)brow * 6144 + ncol] = v;
            }
    }
}

// ---------------------------------------------------------------------------
// W_comb = W_ih[:, :1024] @ W_out on the f16 core; rows<2048 add W_hh;
// write *16 split into INTERLEAVED Wbig rows 4u+g. 384 blocks (24 mt x 16 nt).
// ---------------------------------------------------------------------------
__global__ __launch_bounds__(256) void gemm_wcomb16(
    const _Float16* __restrict__ Wih0, const _Float16* __restrict__ Wih1,
    const _Float16* __restrict__ WoT0, const _Float16* __restrict__ WoT1,
    const float* __restrict__ W_hh,
    _Float16* __restrict__ W0, _Float16* __restrict__ W1)
{
    __shared__ alignas(16) char lds[49152];
    const int bid = blockIdx.x;
    const int mt = bid >> 4, nt = bid & 15;
    f32x4 acc0[4][2] = {}, accL[4][2] = {};
    gemm_core3t(Wih0, Wih1, WoT0, WoT1, mt * 128, nt * 64, lds, acc0, accL);

    const int lane = threadIdx.x & 63, wid = threadIdx.x >> 6;
    const int wr = wid >> 1, wc = wid & 1, l16 = lane & 15, lq = lane >> 4;
#pragma unroll
    for (int ni = 0; ni < 2; ++ni) {
        const int c = nt * 64 + wc * 32 + ni * 16 + l16;       // 0..1023
#pragma unroll
        for (int mi = 0; mi < 4; ++mi)
#pragma unroll
            for (int r = 0; r < 4; ++r) {
                const int i = mt * 128 + wr * 64 + mi * 16 + lq * 4 + r; // 0..3071
                float v = (acc0[mi][ni][r]
                         + accL[mi][ni][r] * (1.f/2048.f)) * (1.f/256.f);
                if (i < 2048) v += W_hh[(size_t)i * 1024 + c];
                const size_t nr = (size_t)(4 * (i & 1023) + (i >> 10)) * 1024 + c;
                _Float16 a, b; split2h(v * 16.0f, a, b);
                W0[nr] = a; W1[nr] = b;
            }
    }
}

// ---------------------------------------------------------------------------
// t=0 GRU update (reads gbuf [gi|gh], writes h32 + f16 planes)
// ---------------------------------------------------------------------------
__global__ __launch_bounds__(256) void ew_t0_16(
    const float* __restrict__ gbuf, float* __restrict__ h32,
    _Float16* __restrict__ hA0, _Float16* __restrict__ hA1)
{
    const int idx = blockIdx.x * 256 + threadIdx.x;   // 0..524287
    const int b = idx >> 10, j = idx & 1023;
    const float* g = gbuf + (size_t)b * 6144;
    const float pr  = g[j]        + g[3072 + j];
    const float pz  = g[1024 + j] + g[4096 + j];
    const float r = 1.f / (1.f + expf(-pr));
    const float z = 1.f / (1.f + expf(-pz));
    const float n = tanhf(g[2048 + j] + r * g[5120 + j]);
    const float h = (1.f - z) * n + z * h32[idx];
    h32[idx] = h;
    split2h(h, hA0[idx], hA1[idx]);
}

// ---------------------------------------------------------------------------
// Prep kernels
// ---------------------------------------------------------------------------
__global__ __launch_bounds__(256) void prep_w16(
    const float* __restrict__ W_ih, const float* __restrict__ W_hh,
    const float* __restrict__ W_out,
    _Float16* __restrict__ Wih0, _Float16* __restrict__ Wih1,
    _Float16* __restrict__ Whh0, _Float16* __restrict__ Whh1,
    _Float16* __restrict__ WoT0, _Float16* __restrict__ WoT1,
    _Float16* __restrict__ W0,   _Float16* __restrict__ W1)
{
    const int idx = blockIdx.x * 256 + threadIdx.x;   // < 3072*1024
    const int n = idx >> 10, k = idx & 1023;
    _Float16 a, b;
    split2h(W_ih[(size_t)n * 1026 + k] * 16.0f, a, b);
    Wih0[idx] = a; Wih1[idx] = b;
    split2h(W_hh[idx] * 16.0f, a, b);
    Whh0[idx] = a; Whh1[idx] = b;
    if (n >= 2048) {                         // gh_n -> interleaved row 4u+3
        const size_t nr = (size_t)(4 * (n - 2048) + 3) * 1024 + k;
        W0[nr] = a; W1[nr] = b;
    }
    if (n < 1024) {                          // W_out rows [4096,5120) + transpose
        split2h(W_out[idx] * 16.0f, a, b);
        W0[(size_t)(4096 + n) * 1024 + k] = a;
        W1[(size_t)(4096 + n) * 1024 + k] = b;
        WoT0[(size_t)k * 1024 + n] = a;
        WoT1[(size_t)k * 1024 + n] = b;
    }
}

__global__ __launch_bounds__(256) void prep_m16(
    const float* __restrict__ enc, const float* __restrict__ h0,
    const float* __restrict__ W_ih,
    const float* __restrict__ b_ih, const float* __restrict__ b_hh,
    const float* __restrict__ b_out,
    _Float16* __restrict__ e0, _Float16* __restrict__ e1,
    _Float16* __restrict__ hA0, _Float16* __restrict__ hA1,
    float* __restrict__ h32, float* __restrict__ bias_big)
{
    const int idx = blockIdx.x * 256 + threadIdx.x;
    if (idx < 524288) {
        split2h(enc[idx], e0[idx], e1[idx]);
        const float hv = h0[idx];
        h32[idx] = hv;
        split2h(hv, hA0[idx], hA1[idx]);
    } else if (idx < 524288 + 5120) {
        const int nn = idx - 524288;
        float v;
        if (nn < 3072) {
            float d = 0.f;
            for (int o = 0; o < 1024; ++o) d += W_ih[(size_t)nn * 1026 + o] * b_out[o];
            v = b_ih[nn] + d + (nn < 2048 ? b_hh[nn] : 0.f);
        } else if (nn < 4096) v = b_hh[nn - 1024];
        else                  v = b_out[nn - 4096];
        bias_big[nn] = v;
    }
}

// ===========================================================================
// fp32 fallback (round-3 verified) for small ws_size.
// ===========================================================================
__global__ __launch_bounds__(256) void gemm_f32(
    const float* __restrict__ A, int lda,
    const float* __restrict__ Bm, int ldb,
    const float* __restrict__ bias,
    const float* __restrict__ act,
    float* __restrict__ dst, int dst_stride, int dst_coloff)
{
    __shared__ float As[16][64];
    __shared__ float Bs[16][64];
    const int t  = threadIdx.x;
    const int tx = t & 15, ty = t >> 4;
    const int row0 = blockIdx.y * 64, col0 = blockIdx.x * 64;
    const int lm = t >> 2;
    const int lk = (t & 3) * 4;
    float acc[4][4] = {};
    for (int kt = 0; kt < 64; ++kt) {
        const int kbase = kt * 16 + lk;
        const float* ap = A + (size_t)(row0 + lm) * lda + kbase;
        const float a0 = ap[0], a1 = ap[1], a2 = ap[2], a3 = ap[3];
        const float* bp = Bm + (size_t)(col0 + lm) * ldb + kbase;
        const float b0 = bp[0], b1 = bp[1], b2 = bp[2], b3 = bp[3];
        __syncthreads();
        As[lk + 0][lm] = a0;   As[lk + 1][lm] = a1;
        As[lk + 2][lm] = a2;   As[lk + 3][lm] = a3;
        Bs[lk + 0][lm] = b0;   Bs[lk + 1][lm] = b1;
        Bs[lk + 2][lm] = b2;   Bs[lk + 3][lm] = b3;
        __syncthreads();
#pragma unroll
        for (int kk = 0; kk < 16; ++kk) {
            const f32x4 a4 = *(const f32x4*)&As[kk][ty * 4];
            const f32x4 b4 = *(const f32x4*)&Bs[kk][tx * 4];
#pragma unroll
            for (int i = 0; i < 4; ++i)
#pragma unroll
                for (int j = 0; j < 4; ++j)
                    acc[i][j] += a4[i] * b4[j];
        }
    }
#pragma unroll
    for (int i = 0; i < 4; ++i) {
        const int row = row0 + ty * 4 + i;
        float a0 = 0.f, a1 = 0.f;
        if (act) { a0 = act[row * 2]; a1 = act[row * 2 + 1]; }
#pragma unroll
        for (int j = 0; j < 4; ++j) {
            const int col = col0 + tx * 4 + j;
            float v = acc[i][j] + (bias ? bias[col] : 0.f);
            if (act) v += a0 * Bm[(size_t)col * ldb + 1024]
                        + a1 * Bm[(size_t)col * ldb + 1025];
            dst[(size_t)row * dst_stride + dst_coloff + col] = v;
        }
    }
}

__global__ __launch_bounds__(256) void ew_gru32(
    const float* __restrict__ gbuf, float* __restrict__ h32)
{
    const int idx = blockIdx.x * 256 + threadIdx.x;
    const int b = idx >> 10, j = idx & 1023;
    const float* g = gbuf + (size_t)b * 6144;
    const float pr  = g[j]        + g[3072 + j];
    const float pz  = g[1024 + j] + g[4096 + j];
    const float r = 1.f / (1.f + expf(-pr));
    const float z = 1.f / (1.f + expf(-pz));
    const float n = tanhf(g[2048 + j] + r * g[5120 + j]);
    h32[idx] = (1.f - z) * n + z * h32[idx];
}

__global__ __launch_bounds__(256) void init_h(const float* __restrict__ h0,
                                              float* __restrict__ h32) {
    const int idx = blockIdx.x * 256 + threadIdx.x;
    h32[idx] = h0[idx];
}

// ---------------------------------------------------------------------------
extern "C" void kernel_launch(void* const* d_in, const int* in_sizes, int n_in,
                              void* d_out, int out_size, void* d_ws, size_t ws_size,
                              hipStream_t stream) {
    const float* enc     = (const float*)d_in[0];
    const float* actions = (const float*)d_in[1];   // [64][512][2]
    const float* h0      = (const float*)d_in[2];
    const float* W_ih    = (const float*)d_in[3];   // [3072][1026]
    const float* W_hh    = (const float*)d_in[4];   // [3072][1024]
    const float* b_ih    = (const float*)d_in[5];
    const float* b_hh    = (const float*)d_in[6];
    const float* W_out   = (const float*)d_in[7];   // [1024][1024]
    const float* b_out   = (const float*)d_in[8];
    float* out = (float*)d_out;                     // [64][512][1024]
    char* ws = (char*)d_ws;

    float* h32  = (float*)ws;                       // 2,097,152 B
    float* gbuf = (float*)(ws + 2097152);           // 12,582,912 -> 14,680,064

    const size_t NEED = 69226496;                   // == r7-proven available
    if (ws_size < NEED) {
        // ---------------- fp32 fallback (round-3 verified) ----------------
        init_h<<<2048, 256, 0, stream>>>(h0, h32);
        const float* e = enc;
        for (int t = 0; t < 64; ++t) {
            gemm_f32<<<dim3(48, 8), 256, 0, stream>>>(
                e, 1024, W_ih, 1026, b_ih, actions + (size_t)t * 1024, gbuf, 6144, 0);
            gemm_f32<<<dim3(48, 8), 256, 0, stream>>>(
                h32, 1024, W_hh, 1024, b_hh, nullptr, gbuf, 6144, 3072);
            ew_gru32<<<2048, 256, 0, stream>>>(gbuf, h32);
            float* ot = out + (size_t)t * 524288;
            gemm_f32<<<dim3(16, 8), 256, 0, stream>>>(
                h32, 1024, W_out, 1024, b_out, nullptr, ot, 1024, 0);
            e = ot;
        }
        return;
    }

    // ---------------- f16 2-plane fused MFMA path ----------------
    size_t off = 14680064;
    auto take = [&](size_t bytes) { char* p = ws + off; off += bytes; return p; };
    _Float16* W0   = (_Float16*)take(10485760);   // interleaved Wbig 5120x1024
    _Float16* W1   = (_Float16*)take(10485760);
    _Float16* Wih0 = (_Float16*)take(6291456);    // 3072x1024 (t0 / wcomb only)
    _Float16* Wih1 = (_Float16*)take(6291456);
    _Float16* Whh0 = (_Float16*)take(6291456);
    _Float16* Whh1 = (_Float16*)take(6291456);
    _Float16* WoT0 = (_Float16*)take(2097152);    // 1024x1024 (wcomb only)
    _Float16* WoT1 = (_Float16*)take(2097152);
    _Float16* e0   = (_Float16*)take(1048576);    // 512x1024
    _Float16* e1   = (_Float16*)take(1048576);
    _Float16* hA0  = (_Float16*)take(1048576);
    _Float16* hA1  = (_Float16*)take(1048576);
    float* bias_big= (float*)take(20480);         // 5120 f32
    // off == 69,226,496
    // h double-buffer B aliased into gbuf (gbuf dead after ew_t0_16):
    _Float16* hB0 = (_Float16*)gbuf;
    _Float16* hB1 = (_Float16*)((char*)gbuf + 1048576);

    prep_w16<<<12288, 256, 0, stream>>>(W_ih, W_hh, W_out,
        Wih0, Wih1, Whh0, Whh1, WoT0, WoT1, W0, W1);
    prep_m16<<<2068, 256, 0, stream>>>(enc, h0, W_ih, b_ih, b_hh, b_out,
        e0, e1, hA0, hA1, h32, bias_big);
    gemm_wcomb16<<<384, 256, 0, stream>>>(Wih0, Wih1, WoT0, WoT1, W_hh, W0, W1);

    // t = 0 (e = enc), then h_1 -> hA.
    gemm_t0_16<<<384, 256, 0, stream>>>(e0, e1, hA0, hA1,
        Wih0, Wih1, Whh0, Whh1, W_ih, b_ih, b_hh, actions, gbuf);
    ew_t0_16<<<2048, 256, 0, stream>>>(gbuf, h32, hA0, hA1);

    // t = 1..63: ONE fused kernel per step (gates+GRU -> h_{t+1}, + out_{t-1})
    _Float16 *c0 = hA0, *c1 = hA1, *n0 = hB0, *n1 = hB1;
    for (int t = 1; t < 64; ++t) {
        gemm_step_fused<<<320, 256, 0, stream>>>(c0, c1, W0, W1, n0, n1, h32,
            out + (size_t)(t - 1) * 524288, bias_big, W_ih,
            actions + (size_t)t * 1024, 0);
        _Float16* s;
        s = c0; c0 = n0; n0 = s;
        s = c1; c1 = n1; n1 = s;
    }
    // out_63 = h_64 @ W_out.T + b_out (out tiles only)
    gemm_step_fused<<<64, 256, 0, stream>>>(c0, c1, W0, W1, n0, n1, h32,
        out + (size_t)63 * 524288, bias_big, W_ih, actions, 64);
}

// Round 14
// 2009.302 us; speedup vs baseline: 6.0830x; 1.5175x over previous
//
#include <hip/hip_runtime.h>
#include <stdint.h>
#include <stddef.h>

// RNNPredictorBurnin — round 14: per-step dispatches (cooperative abandoned
// after r12 refusal + r13 on-GPU deadlock). r11's passing math with two
// occupancy/staging levers:
//   1) 64x64 tile, grid 640 (2.5 blocks/CU vs r11's 1.25) — TLP.
//   2) global_load_lds w=16 staging, linear LDS dest + inverse-swizzled
//      per-lane source (rule #21; r4==r5 bit-identity proved this pattern).
// Math identical to r11: f16 2-plane scaled split, 3 terms (~2^-22), folded
// W_comb, gate-interleaved Wbig, fused GRU epilogue, fp32 master h.

typedef _Float16 f16x8 __attribute__((ext_vector_type(8)));
typedef float f32x4  __attribute__((ext_vector_type(4)));

__device__ __forceinline__ void split2h(float v, _Float16& a, _Float16& b) {
    a = (_Float16)v;
    b = (_Float16)((v - (float)a) * 2048.0f);
}

__device__ __forceinline__ int swz(int row, int col) {   // LDS byte address
    return row * 128 + (col ^ ((row & 7) << 4));
}

__device__ __forceinline__ void gload16(const char* src, char* ldsdst) {
    __builtin_amdgcn_global_load_lds(
        (const __attribute__((address_space(1))) void*)src,
        (__attribute__((address_space(3))) void*)ldsdst, 16, 0, 0);
}

// ===========================================================================
// Step kernel: 64x64 tile, 4 waves, 32KB LDS (A0@0 A1@8K B0@16K B1@24K).
// Staging: 8 global_load_lds per wave per kt (A0:2 A1:2 B0:2 B1:2), each op
// covers 8 rows x 128B; lane l -> row +(l>>3), src col ((l&7)^((l>>3)&7))<<4,
// LDS dest linear (wave-uniform base + 16*lane). Reads use swz().
// Grid: steps 640 = 8 XCD x (8 mt x 10 nt); final 128 = 8 mt x 16 out-nt.
// ===========================================================================
__global__ __launch_bounds__(256) void gemm_step64(
    const _Float16* __restrict__ hc0, const _Float16* __restrict__ hc1,
    const _Float16* __restrict__ W0,  const _Float16* __restrict__ W1,
    _Float16* __restrict__ hn0, _Float16* __restrict__ hn1,
    float* __restrict__ h32,
    float* __restrict__ outp,
    const float* __restrict__ bias_big,
    const float* __restrict__ W_ih,
    const float* __restrict__ act,
    int is_final)
{
    __shared__ alignas(16) char lds[32768];
    const int bid = blockIdx.x;
    int mt, nt;
    if (is_final) { mt = bid & 7; nt = 64 + (bid >> 3); }       // 128 blocks
    else { const int xcd = bid & 7, loc = bid >> 3;             // 640 blocks
           mt = loc & 7; nt = xcd * 10 + (loc >> 3); }          // nt 0..79
    const int nrow0 = (nt < 64) ? nt * 64 : 4096 + (nt - 64) * 64;

    const int tid  = threadIdx.x;
    const int wid  = tid >> 6;
    const int lane = tid & 63;
    const int wr = wid >> 1, wc = wid & 1;
    const int l16 = lane & 15, lq = lane >> 4;
    const int srcsw = (((lane & 7) ^ ((lane >> 3) & 7)) << 4);
    const int lrow = lane >> 3;

    // Per-lane global byte offsets (row part), constant across kt:
    const size_t aoff0 = (size_t)(mt * 64 + wid * 16 + lrow) * 2048 + srcsw;
    const size_t aoff1 = aoff0 + 8 * 2048;
    const size_t boff0 = (size_t)(nrow0 + wid * 16 + lrow) * 2048 + srcsw;
    const size_t boff1 = boff0 + 8 * 2048;
    const int dst0 = (wid * 16) * 128;          // wave-uniform LDS bases
    const int dst1 = (wid * 16 + 8) * 128;

    f32x4 acc0[2][2] = {}, accL[2][2] = {};

    for (int kt = 0; kt < 16; ++kt) {
        const int ko = kt * 128;
        gload16((const char*)hc0 + aoff0 + ko, lds + dst0);
        gload16((const char*)hc0 + aoff1 + ko, lds + dst1);
        gload16((const char*)hc1 + aoff0 + ko, lds + 8192 + dst0);
        gload16((const char*)hc1 + aoff1 + ko, lds + 8192 + dst1);
        gload16((const char*)W0  + boff0 + ko, lds + 16384 + dst0);
        gload16((const char*)W0  + boff1 + ko, lds + 16384 + dst1);
        gload16((const char*)W1  + boff0 + ko, lds + 24576 + dst0);
        gload16((const char*)W1  + boff1 + ko, lds + 24576 + dst1);
        __syncthreads();                      // drains vmcnt before reads

#pragma unroll
        for (int kk = 0; kk < 2; ++kk) {
            const int col = kk * 64 + lq * 16;
            f16x8 af0[2], af1[2], bf0[2], bf1[2];
#pragma unroll
            for (int mi = 0; mi < 2; ++mi) {
                const int ad = swz(wr * 32 + mi * 16 + l16, col);
                af0[mi] = *(const f16x8*)(lds + ad);
                af1[mi] = *(const f16x8*)(lds + 8192 + ad);
            }
#pragma unroll
            for (int ni = 0; ni < 2; ++ni) {
                const int bd = swz(wc * 32 + ni * 16 + l16, col);
                bf0[ni] = *(const f16x8*)(lds + 16384 + bd);
                bf1[ni] = *(const f16x8*)(lds + 24576 + bd);
            }
#pragma unroll
            for (int mi = 0; mi < 2; ++mi)
#pragma unroll
                for (int ni = 0; ni < 2; ++ni)
                    acc0[mi][ni] = __builtin_amdgcn_mfma_f32_16x16x32_f16(
                        af0[mi], bf0[ni], acc0[mi][ni], 0, 0, 0);
#pragma unroll
            for (int mi = 0; mi < 2; ++mi)
#pragma unroll
                for (int ni = 0; ni < 2; ++ni)
                    accL[mi][ni] = __builtin_amdgcn_mfma_f32_16x16x32_f16(
                        af0[mi], bf1[ni], accL[mi][ni], 0, 0, 0);
#pragma unroll
            for (int mi = 0; mi < 2; ++mi)
#pragma unroll
                for (int ni = 0; ni < 2; ++ni)
                    accL[mi][ni] = __builtin_amdgcn_mfma_f32_16x16x32_f16(
                        af1[mi], bf0[ni], accL[mi][ni], 0, 0, 0);
        }
        __syncthreads();                      // reads done before next stage
    }

    // ---- epilogue ----
    if (nt >= 64) {                           // out_{t-1} tile
#pragma unroll
        for (int ni = 0; ni < 2; ++ni) {
            const int oc = (nt - 64) * 64 + wc * 32 + ni * 16 + l16;
            const float bias = bias_big[4096 + oc];
#pragma unroll
            for (int mi = 0; mi < 2; ++mi)
#pragma unroll
                for (int r = 0; r < 4; ++r) {
                    const int brow = mt * 64 + wr * 32 + mi * 16 + lq * 4 + r;
                    const float v = (acc0[mi][ni][r]
                                   + accL[mi][ni][r] * (1.f/2048.f)) * (1.f/16.f)
                                  + bias;
                    outp[(size_t)brow * 1024 + oc] = v;
                }
        }
        return;
    }
    // gate tile: fused GRU update
    const int gate = lane & 3;
#pragma unroll
    for (int ni = 0; ni < 2; ++ni) {
        const int c = nt * 64 + wc * 32 + ni * 16 + l16;   // 0..4095
        const int u = c >> 2;
        const int orig_n = gate * 1024 + u;
        const float bias = bias_big[orig_n];
        float w0 = 0.f, w1 = 0.f;
        if (gate < 3) { w0 = W_ih[(size_t)orig_n * 1026 + 1024];
                        w1 = W_ih[(size_t)orig_n * 1026 + 1025]; }
#pragma unroll
        for (int mi = 0; mi < 2; ++mi)
#pragma unroll
            for (int r = 0; r < 4; ++r) {
                const int brow = mt * 64 + wr * 32 + mi * 16 + lq * 4 + r;
                const float v = (acc0[mi][ni][r]
                               + accL[mi][ni][r] * (1.f/2048.f)) * (1.f/16.f)
                              + bias
                              + act[brow * 2] * w0 + act[brow * 2 + 1] * w1;
                const float o1 = __shfl_xor(v, 1);
                const float o2 = __shfl_xor(v, 2);
                const float o3 = __shfl_xor(v, 3);
                if (gate == 0) {
                    const float rr = 1.f / (1.f + expf(-v));
                    const float zz = 1.f / (1.f + expf(-o1));
                    const float nn = tanhf(o2 + rr * o3);
                    const size_t o = (size_t)brow * 1024 + u;
                    const float hnew = (1.f - zz) * nn + zz * h32[o];
                    h32[o] = hnew;
                    _Float16 a, b; split2h(hnew, a, b);
                    hn0[o] = a; hn1[o] = b;
                }
            }
    }
}

// ===========================================================================
// 128x64 3-term core (one-time t0 / wcomb kernels) — r11-verified, verbatim.
// ===========================================================================
__device__ __forceinline__ void stage_regs(
    const _Float16* __restrict__ A0, const _Float16* __restrict__ A1,
    const _Float16* __restrict__ B0, const _Float16* __restrict__ B1,
    int mrow0, int nrow0, int wid, int lr, int lc, int kt,
    f16x8 (&ra0)[4], f16x8 (&ra1)[4], f16x8 (&rb0)[2], f16x8 (&rb1)[2])
{
    const int koff = kt * 128 + lc;
    const char* a0 = (const char*)A0 + koff;
    const char* a1 = (const char*)A1 + koff;
    const char* b0 = (const char*)B0 + koff;
    const char* b1 = (const char*)B1 + koff;
#pragma unroll
    for (int j = 0; j < 4; ++j) {
        const size_t ro = (size_t)(mrow0 + wid * 32 + j * 8 + lr) * 2048;
        ra0[j] = *(const f16x8*)(a0 + ro);
        ra1[j] = *(const f16x8*)(a1 + ro);
    }
#pragma unroll
    for (int j = 0; j < 2; ++j) {
        const size_t ro = (size_t)(nrow0 + wid * 16 + j * 8 + lr) * 2048;
        rb0[j] = *(const f16x8*)(b0 + ro);
        rb1[j] = *(const f16x8*)(b1 + ro);
    }
}

__device__ __forceinline__ void gemm_core3t(
    const _Float16* __restrict__ A0, const _Float16* __restrict__ A1,
    const _Float16* __restrict__ B0, const _Float16* __restrict__ B1,
    int mrow0, int nrow0, char* lds,
    f32x4 (&acc0)[4][2], f32x4 (&accL)[4][2])
{
    const int tid  = threadIdx.x;
    const int wid  = tid >> 6;
    const int lane = tid & 63;
    const int wr = wid >> 1, wc = wid & 1;
    const int l16 = lane & 15, lq = lane >> 4;
    const int lr = lane >> 3, lc = (lane & 7) << 4;
    const int sw = lc ^ (lr << 4);

    f16x8 pa0[4], pa1[4], pb0[2], pb1[2];
    f16x8 na0[4], na1[4], nb0[2], nb1[2];
    stage_regs(A0, A1, B0, B1, mrow0, nrow0, wid, lr, lc, 0, pa0, pa1, pb0, pb1);

    for (int kt = 0; kt < 16; ++kt) {
        if (kt < 15)
            stage_regs(A0, A1, B0, B1, mrow0, nrow0, wid, lr, lc, kt + 1,
                       na0, na1, nb0, nb1);
        __syncthreads();
#pragma unroll
        for (int j = 0; j < 4; ++j) {
            const int ro = (wid * 32 + j * 8 + lr) * 128 + sw;
            *(f16x8*)(lds + ro)         = pa0[j];
            *(f16x8*)(lds + 16384 + ro) = pa1[j];
        }
#pragma unroll
        for (int j = 0; j < 2; ++j) {
            const int ro = (wid * 16 + j * 8 + lr) * 128 + sw;
            *(f16x8*)(lds + 32768 + ro) = pb0[j];
            *(f16x8*)(lds + 40960 + ro) = pb1[j];
        }
        __syncthreads();

#pragma unroll
        for (int kk = 0; kk < 2; ++kk) {
            const int col = kk * 64 + lq * 16;
            f16x8 af0[4], af1[4], bf0[2], bf1[2];
#pragma unroll
            for (int mi = 0; mi < 4; ++mi) {
                const int ad = swz(wr * 64 + mi * 16 + l16, col);
                af0[mi] = *(const f16x8*)(lds + ad);
                af1[mi] = *(const f16x8*)(lds + 16384 + ad);
            }
#pragma unroll
            for (int ni = 0; ni < 2; ++ni) {
                const int bd = swz(wc * 32 + ni * 16 + l16, col);
                bf0[ni] = *(const f16x8*)(lds + 32768 + bd);
                bf1[ni] = *(const f16x8*)(lds + 40960 + bd);
            }
#pragma unroll
            for (int mi = 0; mi < 4; ++mi)
#pragma unroll
                for (int ni = 0; ni < 2; ++ni)
                    acc0[mi][ni] = __builtin_amdgcn_mfma_f32_16x16x32_f16(
                        af0[mi], bf0[ni], acc0[mi][ni], 0, 0, 0);
#pragma unroll
            for (int mi = 0; mi < 4; ++mi)
#pragma unroll
                for (int ni = 0; ni < 2; ++ni)
                    accL[mi][ni] = __builtin_amdgcn_mfma_f32_16x16x32_f16(
                        af0[mi], bf1[ni], accL[mi][ni], 0, 0, 0);
#pragma unroll
            for (int mi = 0; mi < 4; ++mi)
#pragma unroll
                for (int ni = 0; ni < 2; ++ni)
                    accL[mi][ni] = __builtin_amdgcn_mfma_f32_16x16x32_f16(
                        af1[mi], bf0[ni], accL[mi][ni], 0, 0, 0);
        }
        if (kt < 15) {
#pragma unroll
            for (int j = 0; j < 4; ++j) { pa0[j] = na0[j]; pa1[j] = na1[j]; }
#pragma unroll
            for (int j = 0; j < 2; ++j) { pb0[j] = nb0[j]; pb1[j] = nb1[j]; }
        }
    }
}

// ---------------------------------------------------------------------------
// t=0 GEMM: nt<48 -> gi = enc @ Wih^T ; nt>=48 -> gh = h0 @ Whh^T.
// ---------------------------------------------------------------------------
__global__ __launch_bounds__(256) void gemm_t0_16(
    const _Float16* __restrict__ e0, const _Float16* __restrict__ e1,
    const _Float16* __restrict__ hA0, const _Float16* __restrict__ hA1,
    const _Float16* __restrict__ Wih0, const _Float16* __restrict__ Wih1,
    const _Float16* __restrict__ Whh0, const _Float16* __restrict__ Whh1,
    const float* __restrict__ W_ih,
    const float* __restrict__ b_ih, const float* __restrict__ b_hh,
    const float* __restrict__ act,
    float* __restrict__ gbuf)
{
    __shared__ alignas(16) char lds[49152];
    const int bid = blockIdx.x;
    const int mt = bid & 3, nt = bid >> 2;      // nt 0..95
    const _Float16 *A0, *A1, *B0, *B1; int nr0;
    if (nt < 48) { A0 = e0;  A1 = e1;  B0 = Wih0; B1 = Wih1; nr0 = nt * 64; }
    else         { A0 = hA0; A1 = hA1; B0 = Whh0; B1 = Whh1; nr0 = (nt - 48) * 64; }
    f32x4 acc0[4][2] = {}, accL[4][2] = {};
    gemm_core3t(A0, A1, B0, B1, mt * 128, nr0, lds, acc0, accL);

    const int lane = threadIdx.x & 63, wid = threadIdx.x >> 6;
    const int wr = wid >> 1, wc = wid & 1, l16 = lane & 15, lq = lane >> 4;
#pragma unroll
    for (int ni = 0; ni < 2; ++ni) {
        const int ncol = nt * 64 + wc * 32 + ni * 16 + l16;   // 0..6143
        float bias, w0 = 0.f, w1 = 0.f;
        if (ncol < 3072) {
            bias = b_ih[ncol];
            w0 = W_ih[(size_t)ncol * 1026 + 1024];
            w1 = W_ih[(size_t)ncol * 1026 + 1025];
        } else bias = b_hh[ncol - 3072];
#pragma unroll
        for (int mi = 0; mi < 4; ++mi)
#pragma unroll
            for (int r = 0; r < 4; ++r) {
                const int brow = mt * 128 + wr * 64 + mi * 16 + lq * 4 + r;
                const float v = (acc0[mi][ni][r]
                               + accL[mi][ni][r] * (1.f/2048.f)) * (1.f/16.f)
                              + bias
                              + act[brow * 2] * w0 + act[brow * 2 + 1] * w1;
                gbuf[(size_t)brow * 6144 + ncol] = v;
            }
    }
}

// ---------------------------------------------------------------------------
// W_comb on the f16 core; rows<2048 add W_hh; interleaved rows 4u+g.
// ---------------------------------------------------------------------------
__global__ __launch_bounds__(256) void gemm_wcomb16(
    const _Float16* __restrict__ Wih0, const _Float16* __restrict__ Wih1,
    const _Float16* __restrict__ WoT0, const _Float16* __restrict__ WoT1,
    const float* __restrict__ W_hh,
    _Float16* __restrict__ W0, _Float16* __restrict__ W1)
{
    __shared__ alignas(16) char lds[49152];
    const int bid = blockIdx.x;
    const int mt = bid >> 4, nt = bid & 15;
    f32x4 acc0[4][2] = {}, accL[4][2] = {};
    gemm_core3t(Wih0, Wih1, WoT0, WoT1, mt * 128, nt * 64, lds, acc0, accL);

    const int lane = threadIdx.x & 63, wid = threadIdx.x >> 6;
    const int wr = wid >> 1, wc = wid & 1, l16 = lane & 15, lq = lane >> 4;
#pragma unroll
    for (int ni = 0; ni < 2; ++ni) {
        const int c = nt * 64 + wc * 32 + ni * 16 + l16;       // 0..1023
#pragma unroll
        for (int mi = 0; mi < 4; ++mi)
#pragma unroll
            for (int r = 0; r < 4; ++r) {
                const int i = mt * 128 + wr * 64 + mi * 16 + lq * 4 + r; // 0..3071
                float v = (acc0[mi][ni][r]
                         + accL[mi][ni][r] * (1.f/2048.f)) * (1.f/256.f);
                if (i < 2048) v += W_hh[(size_t)i * 1024 + c];
                const size_t nr = (size_t)(4 * (i & 1023) + (i >> 10)) * 1024 + c;
                _Float16 a, b; split2h(v * 16.0f, a, b);
                W0[nr] = a; W1[nr] = b;
            }
    }
}

// ---------------------------------------------------------------------------
__global__ __launch_bounds__(256) void ew_t0_16(
    const float* __restrict__ gbuf, float* __restrict__ h32,
    _Float16* __restrict__ hA0, _Float16* __restrict__ hA1)
{
    const int idx = blockIdx.x * 256 + threadIdx.x;   // 0..524287
    const int b = idx >> 10, j = idx & 1023;
    const float* g = gbuf + (size_t)b * 6144;
    const float pr  = g[j]        + g[3072 + j];
    const float pz  = g[1024 + j] + g[4096 + j];
    const float r = 1.f / (1.f + expf(-pr));
    const float z = 1.f / (1.f + expf(-pz));
    const float n = tanhf(g[2048 + j] + r * g[5120 + j]);
    const float h = (1.f - z) * n + z * h32[idx];
    h32[idx] = h;
    split2h(h, hA0[idx], hA1[idx]);
}

__global__ __launch_bounds__(256) void prep_w16(
    const float* __restrict__ W_ih, const float* __restrict__ W_hh,
    const float* __restrict__ W_out,
    _Float16* __restrict__ Wih0, _Float16* __restrict__ Wih1,
    _Float16* __restrict__ Whh0, _Float16* __restrict__ Whh1,
    _Float16* __restrict__ WoT0, _Float16* __restrict__ WoT1,
    _Float16* __restrict__ W0,   _Float16* __restrict__ W1)
{
    const int idx = blockIdx.x * 256 + threadIdx.x;   // < 3072*1024
    const int n = idx >> 10, k = idx & 1023;
    _Float16 a, b;
    split2h(W_ih[(size_t)n * 1026 + k] * 16.0f, a, b);
    Wih0[idx] = a; Wih1[idx] = b;
    split2h(W_hh[idx] * 16.0f, a, b);
    Whh0[idx] = a; Whh1[idx] = b;
    if (n >= 2048) {                         // gh_n -> interleaved row 4u+3
        const size_t nr = (size_t)(4 * (n - 2048) + 3) * 1024 + k;
        W0[nr] = a; W1[nr] = b;
    }
    if (n < 1024) {                          // W_out rows [4096,5120) + transpose
        split2h(W_out[idx] * 16.0f, a, b);
        W0[(size_t)(4096 + n) * 1024 + k] = a;
        W1[(size_t)(4096 + n) * 1024 + k] = b;
        WoT0[(size_t)k * 1024 + n] = a;
        WoT1[(size_t)k * 1024 + n] = b;
    }
}

__global__ __launch_bounds__(256) void prep_m16(
    const float* __restrict__ enc, const float* __restrict__ h0,
    const float* __restrict__ W_ih,
    const float* __restrict__ b_ih, const float* __restrict__ b_hh,
    const float* __restrict__ b_out,
    _Float16* __restrict__ e0, _Float16* __restrict__ e1,
    _Float16* __restrict__ hA0, _Float16* __restrict__ hA1,
    float* __restrict__ h32, float* __restrict__ bias_big)
{
    const int idx = blockIdx.x * 256 + threadIdx.x;
    if (idx < 524288) {
        split2h(enc[idx], e0[idx], e1[idx]);
        const float hv = h0[idx];
        h32[idx] = hv;
        split2h(hv, hA0[idx], hA1[idx]);
    } else if (idx < 524288 + 5120) {
        const int nn = idx - 524288;
        float v;
        if (nn < 3072) {
            float d = 0.f;
            for (int o = 0; o < 1024; ++o) d += W_ih[(size_t)nn * 1026 + o] * b_out[o];
            v = b_ih[nn] + d + (nn < 2048 ? b_hh[nn] : 0.f);
        } else if (nn < 4096) v = b_hh[nn - 1024];
        else                  v = b_out[nn - 4096];
        bias_big[nn] = v;
    }
}

// ===========================================================================
// fp32 fallback (round-3 verified) for small ws_size.
// ===========================================================================
__global__ __launch_bounds__(256) void gemm_f32(
    const float* __restrict__ A, int lda,
    const float* __restrict__ Bm, int ldb,
    const float* __restrict__ bias,
    const float* __restrict__ act,
    float* __restrict__ dst, int dst_stride, int dst_coloff)
{
    __shared__ float As[16][64];
    __shared__ float Bs[16][64];
    const int t  = threadIdx.x;
    const int tx = t & 15, ty = t >> 4;
    const int row0 = blockIdx.y * 64, col0 = blockIdx.x * 64;
    const int lm = t >> 2;
    const int lk = (t & 3) * 4;
    float acc[4][4] = {};
    for (int kt = 0; kt < 64; ++kt) {
        const int kbase = kt * 16 + lk;
        const float* ap = A + (size_t)(row0 + lm) * lda + kbase;
        const float a0 = ap[0], a1 = ap[1], a2 = ap[2], a3 = ap[3];
        const float* bp = Bm + (size_t)(col0 + lm) * ldb + kbase;
        const float b0 = bp[0], b1 = bp[1], b2 = bp[2], b3 = bp[3];
        __syncthreads();
        As[lk + 0][lm] = a0;   As[lk + 1][lm] = a1;
        As[lk + 2][lm] = a2;   As[lk + 3][lm] = a3;
        Bs[lk + 0][lm] = b0;   Bs[lk + 1][lm] = b1;
        Bs[lk + 2][lm] = b2;   Bs[lk + 3][lm] = b3;
        __syncthreads();
#pragma unroll
        for (int kk = 0; kk < 16; ++kk) {
            const f32x4 a4 = *(const f32x4*)&As[kk][ty * 4];
            const f32x4 b4 = *(const f32x4*)&Bs[kk][tx * 4];
#pragma unroll
            for (int i = 0; i < 4; ++i)
#pragma unroll
                for (int j = 0; j < 4; ++j)
                    acc[i][j] += a4[i] * b4[j];
        }
    }
#pragma unroll
    for (int i = 0; i < 4; ++i) {
        const int row = row0 + ty * 4 + i;
        float a0 = 0.f, a1 = 0.f;
        if (act) { a0 = act[row * 2]; a1 = act[row * 2 + 1]; }
#pragma unroll
        for (int j = 0; j < 4; ++j) {
            const int col = col0 + tx * 4 + j;
            float v = acc[i][j] + (bias ? bias[col] : 0.f);
            if (act) v += a0 * Bm[(size_t)col * ldb + 1024]
                        + a1 * Bm[(size_t)col * ldb + 1025];
            dst[(size_t)row * dst_stride + dst_coloff + col] = v;
        }
    }
}

__global__ __launch_bounds__(256) void ew_gru32(
    const float* __restrict__ gbuf, float* __restrict__ h32)
{
    const int idx = blockIdx.x * 256 + threadIdx.x;
    const int b = idx >> 10, j = idx & 1023;
    const float* g = gbuf + (size_t)b * 6144;
    const float pr  = g[j]        + g[3072 + j];
    const float pz  = g[1024 + j] + g[4096 + j];
    const float r = 1.f / (1.f + expf(-pr));
    const float z = 1.f / (1.f + expf(-pz));
    const float n = tanhf(g[2048 + j] + r * g[5120 + j]);
    h32[idx] = (1.f - z) * n + z * h32[idx];
}

__global__ __launch_bounds__(256) void init_h(const float* __restrict__ h0,
                                              float* __restrict__ h32) {
    const int idx = blockIdx.x * 256 + threadIdx.x;
    h32[idx] = h0[idx];
}

// ---------------------------------------------------------------------------
extern "C" void kernel_launch(void* const* d_in, const int* in_sizes, int n_in,
                              void* d_out, int out_size, void* d_ws, size_t ws_size,
                              hipStream_t stream) {
    const float* enc     = (const float*)d_in[0];
    const float* actions = (const float*)d_in[1];   // [64][512][2]
    const float* h0      = (const float*)d_in[2];
    const float* W_ih    = (const float*)d_in[3];   // [3072][1026]
    const float* W_hh    = (const float*)d_in[4];   // [3072][1024]
    const float* b_ih    = (const float*)d_in[5];
    const float* b_hh    = (const float*)d_in[6];
    const float* W_out   = (const float*)d_in[7];   // [1024][1024]
    const float* b_out   = (const float*)d_in[8];
    float* out = (float*)d_out;                     // [64][512][1024]
    char* ws = (char*)d_ws;

    float* h32  = (float*)ws;                       // 2,097,152 B
    float* gbuf = (float*)(ws + 2097152);           // 12,582,912 -> 14,680,064

    const size_t NEED = 69226496;                   // == r7-proven available
    if (ws_size < NEED) {
        // ---------------- fp32 fallback (round-3 verified) ----------------
        init_h<<<2048, 256, 0, stream>>>(h0, h32);
        const float* e = enc;
        for (int t = 0; t < 64; ++t) {
            gemm_f32<<<dim3(48, 8), 256, 0, stream>>>(
                e, 1024, W_ih, 1026, b_ih, actions + (size_t)t * 1024, gbuf, 6144, 0);
            gemm_f32<<<dim3(48, 8), 256, 0, stream>>>(
                h32, 1024, W_hh, 1024, b_hh, nullptr, gbuf, 6144, 3072);
            ew_gru32<<<2048, 256, 0, stream>>>(gbuf, h32);
            float* ot = out + (size_t)t * 524288;
            gemm_f32<<<dim3(16, 8), 256, 0, stream>>>(
                h32, 1024, W_out, 1024, b_out, nullptr, ot, 1024, 0);
            e = ot;
        }
        return;
    }

    // ---------------- f16 2-plane fused MFMA path ----------------
    size_t off = 14680064;
    auto take = [&](size_t bytes) { char* p = ws + off; off += bytes; return p; };
    _Float16* W0   = (_Float16*)take(10485760);   // interleaved Wbig 5120x1024
    _Float16* W1   = (_Float16*)take(10485760);
    _Float16* Wih0 = (_Float16*)take(6291456);    // 3072x1024 (t0 / wcomb only)
    _Float16* Wih1 = (_Float16*)take(6291456);
    _Float16* Whh0 = (_Float16*)take(6291456);
    _Float16* Whh1 = (_Float16*)take(6291456);
    _Float16* WoT0 = (_Float16*)take(2097152);    // 1024x1024 (wcomb only)
    _Float16* WoT1 = (_Float16*)take(2097152);
    _Float16* e0   = (_Float16*)take(1048576);    // 512x1024
    _Float16* e1   = (_Float16*)take(1048576);
    _Float16* hA0  = (_Float16*)take(1048576);
    _Float16* hA1  = (_Float16*)take(1048576);
    float* bias_big= (float*)take(20480);         // 5120 f32
    // off == 69,226,496
    // h double-buffer B aliased into gbuf (gbuf dead after ew_t0_16):
    _Float16* hB0 = (_Float16*)gbuf;
    _Float16* hB1 = (_Float16*)((char*)gbuf + 1048576);

    prep_w16<<<12288, 256, 0, stream>>>(W_ih, W_hh, W_out,
        Wih0, Wih1, Whh0, Whh1, WoT0, WoT1, W0, W1);
    prep_m16<<<2068, 256, 0, stream>>>(enc, h0, W_ih, b_ih, b_hh, b_out,
        e0, e1, hA0, hA1, h32, bias_big);
    gemm_wcomb16<<<384, 256, 0, stream>>>(Wih0, Wih1, WoT0, WoT1, W_hh, W0, W1);

    // t = 0 (e = enc), then h_1 -> hA.
    gemm_t0_16<<<384, 256, 0, stream>>>(e0, e1, hA0, hA1,
        Wih0, Wih1, Whh0, Whh1, W_ih, b_ih, b_hh, actions, gbuf);
    ew_t0_16<<<2048, 256, 0, stream>>>(gbuf, h32, hA0, hA1);

    // t = 1..63: one fused kernel per step; then final out-only dispatch.
    _Float16 *c0 = hA0, *c1 = hA1, *n0 = hB0, *n1 = hB1;
    for (int t = 1; t < 64; ++t) {
        gemm_step64<<<640, 256, 0, stream>>>(c0, c1, W0, W1, n0, n1, h32,
            out + (size_t)(t - 1) * 524288, bias_big, W_ih,
            actions + (size_t)t * 1024, 0);
        _Float16* s;
        s = c0; c0 = n0; n0 = s;
        s = c1; c1 = n1; n1 = s;
    }
    gemm_step64<<<128, 256, 0, stream>>>(c0, c1, W0, W1, n0, n1, h32,
        out + (size_t)63 * 524288, bias_big, W_ih, actions, 1);
}